// Round 6
// baseline (240.516 us; speedup 1.0000x reference)
//
#include <hip/hip_runtime.h>
#include <hip/hip_bf16.h>

// ---------------------------------------------------------------------------
// Fused causal MHA forward: x[B,T,C] fp32, w_qkv[3C,C] fp32, w_out[C,C] fp32
// B=4 T=2048 C=1024 H=16 hd=64.  All matmuls in bf16 MFMA, fp32 accumulate.
// Pipeline: convert->bf16 | GEMM qkv | flash-attn | GEMM out-proj (fp32 out).
// ---------------------------------------------------------------------------

typedef __attribute__((ext_vector_type(8))) short bf16x8;
typedef __attribute__((ext_vector_type(4))) float f32x4;
typedef __attribute__((ext_vector_type(16))) float f32x16;

#define GLOBAL_AS __attribute__((address_space(1)))
#define LDS_AS __attribute__((address_space(3)))

__device__ __forceinline__ unsigned short f2b_rne(float f) {
  unsigned u = __float_as_uint(f);
  unsigned r = u + 0x7fffu + ((u >> 16) & 1u);
  return (unsigned short)(r >> 16);
}

__device__ __forceinline__ unsigned cvt_pk_bf16(float lo, float hi) {
  unsigned r;
  asm("v_cvt_pk_bf16_f32 %0, %1, %2" : "=v"(r) : "v"(lo), "v"(hi));
  return r;
}

__device__ __forceinline__ void gload_lds16(const void* g, void* l) {
  __builtin_amdgcn_global_load_lds((const GLOBAL_AS void*)g, (LDS_AS void*)l, 16, 0, 0);
}

// ---------------------------------------------------------------------------
// fp32 -> bf16 conversion (vectorized, grid-stride)
// ---------------------------------------------------------------------------
__global__ void f32_to_bf16_vec(const float* __restrict__ src,
                                unsigned short* __restrict__ dst, int n4) {
  int i = blockIdx.x * blockDim.x + threadIdx.x;
  int stride = gridDim.x * blockDim.x;
  for (; i < n4; i += stride) {
    float4 v = reinterpret_cast<const float4*>(src)[i];
    ushort4 o;
    o.x = f2b_rne(v.x); o.y = f2b_rne(v.y);
    o.z = f2b_rne(v.z); o.w = f2b_rne(v.w);
    reinterpret_cast<ushort4*>(dst)[i] = o;
  }
}

// ---------------------------------------------------------------------------
// NT GEMM: C[M,N] = A[M,K] * B[N,K]^T, bf16 in, fp32 acc. (unchanged)
// ---------------------------------------------------------------------------
template <int OUT_BF16>
__global__ __launch_bounds__(256)
void gemm_nt(const unsigned short* __restrict__ A,
             const unsigned short* __restrict__ B,
             void* __restrict__ Cout, int M, int N, int K) {
  __shared__ __align__(16) unsigned short As[128][32];
  __shared__ __align__(16) unsigned short Bs[128][32];
  const int tid = threadIdx.x;
  const int w = tid >> 6, lane = tid & 63;
  const int l16 = lane & 15, lg = lane >> 4;
  const int wrow = (w >> 1) * 64, wcol = (w & 1) * 64;
  const int m0 = blockIdx.y * 128, n0 = blockIdx.x * 128;

  f32x4 acc[4][4] = {};

  auto stage = [&](int k0) {
#pragma unroll
    for (int c2 = 0; c2 < 2; ++c2) {
      int c = 2 * w + c2;
      const unsigned short* ga =
          A + (size_t)(m0 + 16 * c + (lane >> 2)) * K + k0 + (lane & 3) * 8;
      gload_lds16(ga, &As[16 * c][0]);
      const unsigned short* gb =
          B + (size_t)(n0 + 16 * c + (lane >> 2)) * K + k0 + (lane & 3) * 8;
      gload_lds16(gb, &Bs[16 * c][0]);
    }
  };

  stage(0);
  __syncthreads();
  const int nk = K >> 5;
  for (int ks = 0; ks < nk; ++ks) {
    bf16x8 af[4], bfr[4];
#pragma unroll
    for (int mi = 0; mi < 4; ++mi)
      af[mi] = *(const bf16x8*)&As[wrow + mi * 16 + l16][lg * 8];
#pragma unroll
    for (int ni = 0; ni < 4; ++ni)
      bfr[ni] = *(const bf16x8*)&Bs[wcol + ni * 16 + l16][lg * 8];
    __syncthreads();
    if (ks + 1 < nk) stage((ks + 1) * 32);
#pragma unroll
    for (int mi = 0; mi < 4; ++mi)
#pragma unroll
      for (int ni = 0; ni < 4; ++ni)
        acc[mi][ni] = __builtin_amdgcn_mfma_f32_16x16x32_bf16(
            af[mi], bfr[ni], acc[mi][ni], 0, 0, 0);
    __syncthreads();
  }

#pragma unroll
  for (int mi = 0; mi < 4; ++mi) {
#pragma unroll
    for (int ni = 0; ni < 4; ++ni) {
#pragma unroll
      for (int j = 0; j < 4; ++j) {
        int row = m0 + wrow + mi * 16 + lg * 4 + j;
        int col = n0 + wcol + ni * 16 + l16;
        if (OUT_BF16) {
          ((unsigned short*)Cout)[(size_t)row * N + col] =
              f2b_rne(acc[mi][ni][j]);
        } else {
          ((float*)Cout)[(size_t)row * N + col] = acc[mi][ni][j];
        }
      }
    }
  }
}

// ---------------------------------------------------------------------------
// Flash attention fwd, causal; swapped-QK^T 32x32 structure.
// Uniform-work pairing: each block runs TWO q-tiles, qtA=15-p (heavy) then
// qtB=p (light): exactly 34 KV tiles per block -> zero load-imbalance tail.
// Single staging pipeline spans both segments (no bubble at the boundary).
// KV tile 64, double-buffered; 1 barrier/tile; XCD-swizzled grid (512 blks).
// ---------------------------------------------------------------------------
__global__ __launch_bounds__(256)
void attn_fwd(const unsigned short* __restrict__ qkv,
              unsigned short* __restrict__ out) {
  const int T = 2048, C3 = 3072;
  __shared__ __align__(16) unsigned short Ks[2][64][64];  // block-swizzled
  __shared__ __align__(16) unsigned short Vt[2][64][64];  // [d][kv], swizzled
  __shared__ float Bc[4][32];                             // per-wave broadcast

  const int tid = threadIdx.x, w = tid >> 6, lane = tid & 63;
  const int l31 = lane & 31, h = lane >> 5;
  // XCD swizzle: 512 blocks = 8 XCDs x 64. XCD k gets bh in [8k, 8k+8).
  const int wgid = (blockIdx.x & 7) * 64 + (blockIdx.x >> 3);
  const int bh = wgid >> 3, p = wgid & 7;
  const int qtA = 15 - p, qtB = p;
  const int b = bh >> 4, hed = bh & 15;
  const size_t rowbase = (size_t)b * T * C3;
  const int hoff = hed * 64;

  auto stageK = [&](int kvr, int buf) {
#pragma unroll
    for (int pp = 0; pp < 2; ++pp) {
      int chunk = w * 2 + pp;
      int row = chunk * 8 + (lane >> 3);
      int blk = (lane & 7) ^ (lane >> 3);
      gload_lds16(
          qkv + rowbase + (size_t)(kvr + row) * C3 + 1024 + hoff + blk * 8,
          &Ks[buf][chunk * 8][0]);
    }
  };
  auto loadV = [&](int kvr, bf16x8* vv) {
#pragma unroll
    for (int pp = 0; pp < 2; ++pp) {
      int r = pp * 32 + (tid >> 3);
      vv[pp] = *(const bf16x8*)(qkv + rowbase + (size_t)(kvr + r) * C3 +
                                2048 + hoff + (tid & 7) * 8);
    }
  };
  auto writeV = [&](bf16x8* vv, int buf) {
#pragma unroll
    for (int pp = 0; pp < 2; ++pp) {
      int r = pp * 32 + (tid >> 3);
      int c = (tid & 7) * 8;
      int g = r >> 3;
#pragma unroll
      for (int i = 0; i < 8; ++i) {
        int d = c + i;
        Vt[buf][d][((g ^ ((d >> 3) & 7)) * 8) + (r & 7)] =
            (unsigned short)vv[pp][i];
      }
    }
  };
  auto loadQ = [&](int qw, bf16x8* qf) {
    const unsigned short* qp =
        qkv + rowbase + (size_t)(qw + l31) * C3 + hoff + h * 8;
#pragma unroll
    for (int s = 0; s < 4; ++s) qf[s] = *(const bf16x8*)(qp + 16 * s);
  };

  const int qwA = qtA * 128 + w * 32, qwB = qtB * 128 + w * 32;
  bf16x8 qf[4], qfB[4];
  loadQ(qwA, qf);
  loadQ(qwB, qfB);

  f32x16 oacc[2] = {};  // O: col d = 32dt + l31, rows q spread over regs
  float m_r = -1e30f, sum = 0.f;
  int qw = qwA;

  auto storeO = [&](int qw_s) {
    if (h == 0) Bc[w][l31] = 1.0f / sum;
    asm volatile("s_waitcnt lgkmcnt(0)" ::: "memory");
#pragma unroll
    for (int r = 0; r < 16; ++r) {
      int ql = (r & 3) + 8 * (r >> 2) + 4 * h;
      float inv = Bc[w][ql];
      int q_abs = qw_s + ql;
#pragma unroll
      for (int dt = 0; dt < 2; ++dt) {
        out[(size_t)(b * T + q_abs) * 1024 + hoff + dt * 32 + l31] =
            f2b_rne(oacc[dt][r] * inv);
      }
    }
  };

  const int ntA = 2 * qtA + 2;  // + ntB = 34 total, uniform per block
  // prologue: stage first tile of segment A
  {
    bf16x8 vv[2];
    stageK(0, 0);
    loadV(0, vv);
    writeV(vv, 0);
  }
  __syncthreads();

  int cur = 0;
  for (int tt = 0; tt < 34; ++tt) {
    if (tt == ntA) {  // segment boundary: flush A, reset, switch to B
      storeO(qwA);
      m_r = -1e30f;
      sum = 0.f;
      oacc[0] = (f32x16)0.f;
      oacc[1] = (f32x16)0.f;
      qf[0] = qfB[0]; qf[1] = qfB[1]; qf[2] = qfB[2]; qf[3] = qfB[3];
      qw = qwB;
    }
    const int kv0 = (tt < ntA ? tt : tt - ntA) * 64;
    const bool have_next = (tt + 1 < 34);
    bf16x8 vv[2];
    if (have_next) {  // issue next-tile loads early (fly under compute)
      const int nx = tt + 1;
      const int kvn = (nx < ntA ? nx : nx - ntA) * 64;
      stageK(kvn, cur ^ 1);
      loadV(kvn, vv);
    }

    if (kv0 <= qw) {  // wave-uniform causal participation
      // ---- S^T = K Q^T : sacc[kt] rows kv = 32kt + (r&3)+8(r>>2)+4h ----
      f32x16 sacc[2] = {};
#pragma unroll
      for (int s = 0; s < 4; ++s) {
#pragma unroll
        for (int kt = 0; kt < 2; ++kt) {
          int row = kt * 32 + l31;
          int blk = (2 * s + h) ^ (row & 7);
          bf16x8 kf = *(const bf16x8*)&Ks[cur][row][blk * 8];
          sacc[kt] = __builtin_amdgcn_mfma_f32_32x32x16_bf16(kf, qf[s],
                                                             sacc[kt], 0, 0, 0);
        }
      }
      // ---- causal mask (diagonal tiles only) ----
      if (kv0 + 64 > qw) {
        int q_abs = qw + l31;
#pragma unroll
        for (int kt = 0; kt < 2; ++kt)
#pragma unroll
          for (int r = 0; r < 16; ++r) {
            int kv_abs = kv0 + kt * 32 + (r & 3) + 8 * (r >> 2) + 4 * h;
            if (kv_abs > q_abs) sacc[kt][r] = -1e30f;
          }
      }
      // ---- tile max (in-lane tree + one partner shfl) ----
      float tm = sacc[0][0];
#pragma unroll
      for (int r = 1; r < 16; ++r) tm = fmaxf(tm, sacc[0][r]);
#pragma unroll
      for (int r = 0; r < 16; ++r) tm = fmaxf(tm, sacc[1][r]);
      tm = fmaxf(tm, __shfl_xor(tm, 32));
      if (kv0 == 0) {
        m_r = tm;
      } else if (!__all(tm <= m_r + 16.0f)) {
        float mnew = fmaxf(m_r, tm);
        float corr = __expf((m_r - mnew) * 0.125f);
        sum *= corr;
        if (h == 0) Bc[w][l31] = corr;
        m_r = mnew;
        asm volatile("s_waitcnt lgkmcnt(0)" ::: "memory");
#pragma unroll
        for (int r = 0; r < 16; ++r) {
          float cr = Bc[w][(r & 3) + 8 * (r >> 2) + 4 * h];
          oacc[0][r] *= cr;
          oacc[1][r] *= cr;
        }
      }
      // ---- P = exp(0.125(s - m)), in-register; accumulate sum ----
      float m8 = m_r * 0.125f;
      float sl = 0.f;
#pragma unroll
      for (int kt = 0; kt < 2; ++kt)
#pragma unroll
        for (int r = 0; r < 16; ++r) {
          float pv = __expf(fmaf(sacc[kt][r], 0.125f, -m8));
          sacc[kt][r] = pv;
          sl += pv;
        }
      sum += sl + __shfl_xor(sl, 32);
      // ---- pack P pairs to bf16 ----
      unsigned pk[16];
#pragma unroll
      for (int kt = 0; kt < 2; ++kt)
#pragma unroll
        for (int r = 0; r < 16; r += 2)
          pk[kt * 8 + (r >> 1)] = cvt_pk_bf16(sacc[kt][r], sacc[kt][r + 1]);
      // ---- PV: assemble A-frags in regs, accumulate ----
#pragma unroll
      for (int sg = 0; sg < 4; ++sg) {
        const int kt = sg >> 1, s = sg & 1;
        const int base = kt * 8 + 4 * s;
        unsigned ra = (unsigned)__shfl_xor((int)pk[base], 32);
        unsigned rb = (unsigned)__shfl_xor((int)pk[base + 1], 32);
        unsigned rc = (unsigned)__shfl_xor((int)pk[base + 2], 32);
        unsigned rd = (unsigned)__shfl_xor((int)pk[base + 3], 32);
        union { unsigned u[4]; bf16x8 v; } A;
        A.u[0] = h ? rc : pk[base];
        A.u[1] = h ? rd : pk[base + 1];
        A.u[2] = h ? pk[base + 2] : ra;
        A.u[3] = h ? pk[base + 3] : rb;
#pragma unroll
        for (int dt = 0; dt < 2; ++dt) {
          int d = dt * 32 + l31;
          int blk = (2 * sg + h) ^ ((d >> 3) & 7);
          bf16x8 vf = *(const bf16x8*)&Vt[cur][d][blk * 8];
          oacc[dt] = __builtin_amdgcn_mfma_f32_32x32x16_bf16(A.v, vf,
                                                             oacc[dt], 0, 0, 0);
        }
      }
    }

    if (have_next) writeV(vv, cur ^ 1);  // drain V loads after compute
    __syncthreads();                     // next tile ready; prev reads done
    cur ^= 1;
  }

  storeO(qwB);  // flush segment B
}

// ---------------------------------------------------------------------------
extern "C" void kernel_launch(void* const* d_in, const int* in_sizes, int n_in,
                              void* d_out, int out_size, void* d_ws,
                              size_t ws_size, hipStream_t stream) {
  const float* x = (const float*)d_in[0];      // [4,2048,1024]
  const float* w_qkv = (const float*)d_in[1];  // [3072,1024]
  const float* w_out = (const float*)d_in[2];  // [1024,1024]
  float* out = (float*)d_out;                  // [4,2048,1024] fp32

  const int M = 8192, C = 1024, C3 = 3072;

  unsigned short* xb = (unsigned short*)d_ws;           // M*C
  unsigned short* wqkvb = xb + (size_t)M * C;           // C3*C
  unsigned short* woutb = wqkvb + (size_t)C3 * C;       // C*C
  unsigned short* qkv = woutb + (size_t)C * C;          // M*C3
  unsigned short* attno = qkv + (size_t)M * C3;         // M*C

  f32_to_bf16_vec<<<1024, 256, 0, stream>>>(x, xb, M * C / 4);
  f32_to_bf16_vec<<<512, 256, 0, stream>>>(w_qkv, wqkvb, C3 * C / 4);
  f32_to_bf16_vec<<<256, 256, 0, stream>>>(w_out, woutb, C * C / 4);

  gemm_nt<1><<<dim3(C3 / 128, M / 128), 256, 0, stream>>>(xb, wqkvb, qkv, M, C3, C);

  attn_fwd<<<512, 256, 0, stream>>>(qkv, attno);

  gemm_nt<0><<<dim3(C / 128, M / 128), 256, 0, stream>>>(attno, woutb, out, M, C, C);
}

// Round 7
// 225.350 us; speedup vs baseline: 1.0673x; 1.0673x over previous
//
#include <hip/hip_runtime.h>
#include <hip/hip_bf16.h>

// ---------------------------------------------------------------------------
// Fused causal MHA forward: x[B,T,C] fp32, w_qkv[3C,C] fp32, w_out[C,C] fp32
// B=4 T=2048 C=1024 H=16 hd=64.  All matmuls in bf16 MFMA, fp32 accumulate.
// convert->bf16 | GEMM qkv (V written transposed) | flash-attn | GEMM out.
// ---------------------------------------------------------------------------

typedef __attribute__((ext_vector_type(8))) short bf16x8;
typedef __attribute__((ext_vector_type(4))) float f32x4;
typedef __attribute__((ext_vector_type(16))) float f32x16;
typedef __attribute__((ext_vector_type(2))) unsigned uint2v;

#define GLOBAL_AS __attribute__((address_space(1)))
#define LDS_AS __attribute__((address_space(3)))

__device__ __forceinline__ unsigned short f2b_rne(float f) {
  unsigned u = __float_as_uint(f);
  unsigned r = u + 0x7fffu + ((u >> 16) & 1u);
  return (unsigned short)(r >> 16);
}

__device__ __forceinline__ unsigned cvt_pk_bf16(float lo, float hi) {
  unsigned r;
  asm("v_cvt_pk_bf16_f32 %0, %1, %2" : "=v"(r) : "v"(lo), "v"(hi));
  return r;
}

__device__ __forceinline__ void gload_lds16(const void* g, void* l) {
  __builtin_amdgcn_global_load_lds((const GLOBAL_AS void*)g, (LDS_AS void*)l, 16, 0, 0);
}

// ---------------------------------------------------------------------------
// fp32 -> bf16 conversion (vectorized, grid-stride)
// ---------------------------------------------------------------------------
__global__ void f32_to_bf16_vec(const float* __restrict__ src,
                                unsigned short* __restrict__ dst, int n4) {
  int i = blockIdx.x * blockDim.x + threadIdx.x;
  int stride = gridDim.x * blockDim.x;
  for (; i < n4; i += stride) {
    float4 v = reinterpret_cast<const float4*>(src)[i];
    ushort4 o;
    o.x = f2b_rne(v.x); o.y = f2b_rne(v.y);
    o.z = f2b_rne(v.z); o.w = f2b_rne(v.w);
    reinterpret_cast<ushort4*>(dst)[i] = o;
  }
}

// ---------------------------------------------------------------------------
// NT GEMM: C[M,N] = A[M,K] * B[N,K]^T, bf16 in, fp32 acc.
// MODE 1 (qkv): bf16 out; cols >= 2048 (the V block) are stored TRANSPOSED
// into vt[bh][d][T] so attention can stage V^T via global_load_lds.
// MODE 0 (proj): fp32 out.
// ---------------------------------------------------------------------------
template <int MODE>
__global__ __launch_bounds__(256)
void gemm_nt(const unsigned short* __restrict__ A,
             const unsigned short* __restrict__ B,
             void* __restrict__ Cout, unsigned short* __restrict__ vt,
             int M, int N, int K) {
  __shared__ __align__(16) unsigned short As[128][32];
  __shared__ __align__(16) unsigned short Bs[128][32];
  const int tid = threadIdx.x;
  const int w = tid >> 6, lane = tid & 63;
  const int l16 = lane & 15, lg = lane >> 4;
  const int wrow = (w >> 1) * 64, wcol = (w & 1) * 64;
  const int m0 = blockIdx.y * 128, n0 = blockIdx.x * 128;

  f32x4 acc[4][4] = {};

  auto stage = [&](int k0) {
#pragma unroll
    for (int c2 = 0; c2 < 2; ++c2) {
      int c = 2 * w + c2;
      const unsigned short* ga =
          A + (size_t)(m0 + 16 * c + (lane >> 2)) * K + k0 + (lane & 3) * 8;
      gload_lds16(ga, &As[16 * c][0]);
      const unsigned short* gb =
          B + (size_t)(n0 + 16 * c + (lane >> 2)) * K + k0 + (lane & 3) * 8;
      gload_lds16(gb, &Bs[16 * c][0]);
    }
  };

  stage(0);
  __syncthreads();
  const int nk = K >> 5;
  for (int ks = 0; ks < nk; ++ks) {
    bf16x8 af[4], bfr[4];
#pragma unroll
    for (int mi = 0; mi < 4; ++mi)
      af[mi] = *(const bf16x8*)&As[wrow + mi * 16 + l16][lg * 8];
#pragma unroll
    for (int ni = 0; ni < 4; ++ni)
      bfr[ni] = *(const bf16x8*)&Bs[wcol + ni * 16 + l16][lg * 8];
    __syncthreads();
    if (ks + 1 < nk) stage((ks + 1) * 32);
#pragma unroll
    for (int mi = 0; mi < 4; ++mi)
#pragma unroll
      for (int ni = 0; ni < 4; ++ni)
        acc[mi][ni] = __builtin_amdgcn_mfma_f32_16x16x32_bf16(
            af[mi], bfr[ni], acc[mi][ni], 0, 0, 0);
    __syncthreads();
  }

#pragma unroll
  for (int mi = 0; mi < 4; ++mi) {
#pragma unroll
    for (int ni = 0; ni < 4; ++ni) {
      const int colbase = n0 + wcol + ni * 16;  // wave-uniform
#pragma unroll
      for (int j = 0; j < 4; ++j) {
        int row = m0 + wrow + mi * 16 + lg * 4 + j;
        int col = colbase + l16;
        if (MODE == 1) {
          if (colbase >= 2048) {  // V block -> transposed store
            int ch = col - 2048;
            int hh = ch >> 6, d = ch & 63;
            int bb = row >> 11, tt = row & 2047;
            vt[((size_t)(bb * 16 + hh) * 64 + d) * 2048 + tt] =
                f2b_rne(acc[mi][ni][j]);
          } else {
            ((unsigned short*)Cout)[(size_t)row * N + col] =
                f2b_rne(acc[mi][ni][j]);
          }
        } else {
          ((float*)Cout)[(size_t)row * N + col] = acc[mi][ni][j];
        }
      }
    }
  }
}

// ---------------------------------------------------------------------------
// Flash attention fwd, causal; swapped-QK^T 32x32 structure.
// Block: 4 waves x 32 q-rows = 128 q. KV tile 64, double-buffered; both K and
// V^T staged via global_load_lds with XOR-swizzled source (conflict-free b128
// reads, zero ds_writes). One barrier per tile; loads fly under compute.
// Softmax fully in-register (exp2-folded); PV frags via permlane32_swap.
// ---------------------------------------------------------------------------
__global__ __launch_bounds__(256)
void attn_fwd(const unsigned short* __restrict__ qkv,
              const unsigned short* __restrict__ vt,
              unsigned short* __restrict__ out) {
  const int T = 2048, C3 = 3072;
  __shared__ __align__(16) unsigned short Ks[2][64][64];  // [kv][d] swizzled
  __shared__ __align__(16) unsigned short Vs[2][64][64];  // [d][kv] swizzled
  __shared__ float Bc[4][32];                             // per-wave broadcast

  const int tid = threadIdx.x, w = tid >> 6, lane = tid & 63;
  const int l31 = lane & 31, h = lane >> 5;
  // XCD swizzle: 1024 blocks = 8 XCDs x 128; qt descending (heavy first).
  const int wgid = (blockIdx.x & 7) * 128 + (blockIdx.x >> 3);
  const int qt = 15 - (wgid & 15);
  const int bh = wgid >> 4;
  const int b = bh >> 4, hed = bh & 15;
  const int qw = qt * 128 + w * 32;
  const size_t rowbase = (size_t)b * T * C3;
  const int hoff = hed * 64;
  const unsigned short* vbase = vt + (size_t)bh * 64 * 2048;
  const float c2 = 0.18033688f;  // 0.125 * log2(e)

  auto stageK = [&](int kv0, int buf) {
#pragma unroll
    for (int pp = 0; pp < 2; ++pp) {
      int chunk = w * 2 + pp;
      int row = chunk * 8 + (lane >> 3);
      int blk = (lane & 7) ^ (lane >> 3);
      gload_lds16(
          qkv + rowbase + (size_t)(kv0 + row) * C3 + 1024 + hoff + blk * 8,
          &Ks[buf][chunk * 8][0]);
    }
  };
  auto stageV = [&](int kv0, int buf) {
#pragma unroll
    for (int pp = 0; pp < 2; ++pp) {
      int chunk = w * 2 + pp;
      int drow = chunk * 8 + (lane >> 3);
      int blk = (lane & 7) ^ (lane >> 3);
      gload_lds16(vbase + (size_t)drow * 2048 + kv0 + blk * 8,
                  &Vs[buf][chunk * 8][0]);
    }
  };

  // Q as B-operand frags: qf[s] = Q[qw + l31][hoff + 16s + 8h .. +8)
  bf16x8 qf[4];
  {
    const unsigned short* qp =
        qkv + rowbase + (size_t)(qw + l31) * C3 + hoff + h * 8;
#pragma unroll
    for (int s = 0; s < 4; ++s) qf[s] = *(const bf16x8*)(qp + 16 * s);
  }

  f32x16 oacc[2] = {};  // O: col d = 32dt + l31, rows q spread over regs
  float m_r = -1e30f, sum = 0.f;

  stageK(0, 0);
  stageV(0, 0);
  __syncthreads();

  int cur = 0;
  const int ntiles = qt * 2 + 2;
  for (int t = 0; t < ntiles; ++t) {
    const int kv0 = t * 64;
    if (t + 1 < ntiles) {  // issue next-tile loads early (fly under compute)
      stageK(kv0 + 64, cur ^ 1);
      stageV(kv0 + 64, cur ^ 1);
    }

    if (kv0 <= qw) {  // wave-uniform causal participation
      // ---- S^T = K Q^T : sacc[kt] rows kv = 32kt + (r&3)+8(r>>2)+4h ----
      f32x16 sacc[2] = {};
      __builtin_amdgcn_s_setprio(1);
#pragma unroll
      for (int s = 0; s < 4; ++s) {
#pragma unroll
        for (int kt = 0; kt < 2; ++kt) {
          int row = kt * 32 + l31;
          int blk = (2 * s + h) ^ (row & 7);
          bf16x8 kf = *(const bf16x8*)&Ks[cur][row][blk * 8];
          sacc[kt] = __builtin_amdgcn_mfma_f32_32x32x16_bf16(kf, qf[s],
                                                             sacc[kt], 0, 0, 0);
        }
      }
      __builtin_amdgcn_s_setprio(0);
      // ---- causal mask (diagonal tiles only) ----
      if (kv0 + 64 > qw) {
        int q_abs = qw + l31;
#pragma unroll
        for (int kt = 0; kt < 2; ++kt)
#pragma unroll
          for (int r = 0; r < 16; ++r) {
            int kv_abs = kv0 + kt * 32 + (r & 3) + 8 * (r >> 2) + 4 * h;
            if (kv_abs > q_abs) sacc[kt][r] = -1e30f;
          }
      }
      // ---- tile max: 3-level tree + one partner shfl ----
      float mx[8];
#pragma unroll
      for (int g = 0; g < 8; ++g)
        mx[g] = fmaxf(fmaxf(sacc[g >> 2][(g & 3) * 4 + 0],
                            sacc[g >> 2][(g & 3) * 4 + 1]),
                      fmaxf(sacc[g >> 2][(g & 3) * 4 + 2],
                            sacc[g >> 2][(g & 3) * 4 + 3]));
      float tm = fmaxf(fmaxf(fmaxf(mx[0], mx[1]), fmaxf(mx[2], mx[3])),
                       fmaxf(fmaxf(mx[4], mx[5]), fmaxf(mx[6], mx[7])));
      tm = fmaxf(tm, __shfl_xor(tm, 32));
      if (t == 0) {
        m_r = tm;
      } else if (!__all(tm <= m_r + 16.0f)) {
        float mnew = fmaxf(m_r, tm);
        float corr = __builtin_amdgcn_exp2f((m_r - mnew) * c2);
        sum *= corr;
        if (h == 0) Bc[w][l31] = corr;
        m_r = mnew;
        asm volatile("s_waitcnt lgkmcnt(0)" ::: "memory");
#pragma unroll
        for (int r = 0; r < 16; ++r) {
          float cr = Bc[w][(r & 3) + 8 * (r >> 2) + 4 * h];
          oacc[0][r] *= cr;
          oacc[1][r] *= cr;
        }
      }
      // ---- P = exp2(c2*(s - m)), in-register; accumulate sum ----
      float m2 = m_r * c2;
      float s0 = 0.f, s1 = 0.f, s2 = 0.f, s3 = 0.f;
#pragma unroll
      for (int kt = 0; kt < 2; ++kt)
#pragma unroll
        for (int r = 0; r < 16; r += 4) {
          float p0 = __builtin_amdgcn_exp2f(fmaf(sacc[kt][r + 0], c2, -m2));
          float p1 = __builtin_amdgcn_exp2f(fmaf(sacc[kt][r + 1], c2, -m2));
          float p2 = __builtin_amdgcn_exp2f(fmaf(sacc[kt][r + 2], c2, -m2));
          float p3 = __builtin_amdgcn_exp2f(fmaf(sacc[kt][r + 3], c2, -m2));
          sacc[kt][r + 0] = p0; sacc[kt][r + 1] = p1;
          sacc[kt][r + 2] = p2; sacc[kt][r + 3] = p3;
          s0 += p0; s1 += p1; s2 += p2; s3 += p3;
        }
      float sl = (s0 + s1) + (s2 + s3);
      sum += sl + __shfl_xor(sl, 32);
      // ---- pack P pairs to bf16 ----
      unsigned pk[16];
#pragma unroll
      for (int kt = 0; kt < 2; ++kt)
#pragma unroll
        for (int r = 0; r < 16; r += 2)
          pk[kt * 8 + (r >> 1)] = cvt_pk_bf16(sacc[kt][r], sacc[kt][r + 1]);
      // ---- PV: A-frags via permlane32_swap (half-exchange), accumulate ----
      __builtin_amdgcn_s_setprio(1);
#pragma unroll
      for (int sg = 0; sg < 4; ++sg) {
        const int kt = sg >> 1, s = sg & 1;
        const int base = kt * 8 + 4 * s;
        uint2v r02 = __builtin_amdgcn_permlane32_swap(pk[base], pk[base + 2],
                                                      false, false);
        uint2v r13 = __builtin_amdgcn_permlane32_swap(pk[base + 1], pk[base + 3],
                                                      false, false);
        union { unsigned u[4]; bf16x8 v; } A;
        A.u[0] = r02.x; A.u[1] = r13.x;
        A.u[2] = r02.y; A.u[3] = r13.y;
#pragma unroll
        for (int dt = 0; dt < 2; ++dt) {
          int d = dt * 32 + l31;
          int blk = (2 * sg + h) ^ (d & 7);
          bf16x8 vf = *(const bf16x8*)&Vs[cur][d][blk * 8];
          oacc[dt] = __builtin_amdgcn_mfma_f32_32x32x16_bf16(A.v, vf,
                                                             oacc[dt], 0, 0, 0);
        }
      }
      __builtin_amdgcn_s_setprio(0);
    }

    __syncthreads();  // staged tile ready; prev reads done
    cur ^= 1;
  }

  // ---- epilogue: broadcast 1/sum[q] to O-layout, store bf16 ----
  if (h == 0) Bc[w][l31] = 1.0f / sum;
  asm volatile("s_waitcnt lgkmcnt(0)" ::: "memory");
#pragma unroll
  for (int r = 0; r < 16; ++r) {
    int ql = (r & 3) + 8 * (r >> 2) + 4 * h;
    float inv = Bc[w][ql];
    int q_abs = qw + ql;
#pragma unroll
    for (int dt = 0; dt < 2; ++dt) {
      out[(size_t)(b * T + q_abs) * 1024 + hoff + dt * 32 + l31] =
          f2b_rne(oacc[dt][r] * inv);
    }
  }
}

// ---------------------------------------------------------------------------
extern "C" void kernel_launch(void* const* d_in, const int* in_sizes, int n_in,
                              void* d_out, int out_size, void* d_ws,
                              size_t ws_size, hipStream_t stream) {
  const float* x = (const float*)d_in[0];      // [4,2048,1024]
  const float* w_qkv = (const float*)d_in[1];  // [3072,1024]
  const float* w_out = (const float*)d_in[2];  // [1024,1024]
  float* out = (float*)d_out;                  // [4,2048,1024] fp32

  const int M = 8192, C = 1024, C3 = 3072;

  unsigned short* xb = (unsigned short*)d_ws;      // M*C  (reused as attno)
  unsigned short* wqkvb = xb + (size_t)M * C;      // C3*C
  unsigned short* woutb = wqkvb + (size_t)C3 * C;  // C*C
  unsigned short* qkv = woutb + (size_t)C * C;     // M*C3 (V region unused)
  unsigned short* vtb = qkv + (size_t)M * C3;      // B*H*64*T = M*C
  unsigned short* attno = xb;                      // alias: xb dead post-GEMM1

  f32_to_bf16_vec<<<1024, 256, 0, stream>>>(x, xb, M * C / 4);
  f32_to_bf16_vec<<<512, 256, 0, stream>>>(w_qkv, wqkvb, C3 * C / 4);
  f32_to_bf16_vec<<<256, 256, 0, stream>>>(w_out, woutb, C * C / 4);

  // qkv = x @ w_qkv^T ; V block stored transposed into vtb
  gemm_nt<1><<<dim3(C3 / 128, M / 128), 256, 0, stream>>>(xb, wqkvb, qkv, vtb,
                                                          M, C3, C);

  attn_fwd<<<1024, 256, 0, stream>>>(qkv, vtb, attno);

  gemm_nt<0><<<dim3(C / 128, M / 128), 256, 0, stream>>>(attno, woutb, out,
                                                         nullptr, M, C, C);
}

// Round 8
// 222.441 us; speedup vs baseline: 1.0813x; 1.0131x over previous
//
#include <hip/hip_runtime.h>
#include <hip/hip_bf16.h>

// ---------------------------------------------------------------------------
// Fused causal MHA forward: x[B,T,C] fp32, w_qkv[3C,C] fp32, w_out[C,C] fp32
// B=4 T=2048 C=1024 H=16 hd=64.  All matmuls in bf16 MFMA, fp32 accumulate.
// convert->bf16 | GEMM qkv | V-transpose | flash-attn | GEMM out-proj.
// ---------------------------------------------------------------------------

typedef __attribute__((ext_vector_type(8))) short bf16x8;
typedef __attribute__((ext_vector_type(4))) float f32x4;
typedef __attribute__((ext_vector_type(16))) float f32x16;
typedef __attribute__((ext_vector_type(2))) unsigned uint2v;

#define GLOBAL_AS __attribute__((address_space(1)))
#define LDS_AS __attribute__((address_space(3)))

__device__ __forceinline__ unsigned short f2b_rne(float f) {
  unsigned u = __float_as_uint(f);
  unsigned r = u + 0x7fffu + ((u >> 16) & 1u);
  return (unsigned short)(r >> 16);
}

__device__ __forceinline__ unsigned cvt_pk_bf16(float lo, float hi) {
  unsigned r;
  asm("v_cvt_pk_bf16_f32 %0, %1, %2" : "=v"(r) : "v"(lo), "v"(hi));
  return r;
}

__device__ __forceinline__ void gload_lds16(const void* g, void* l) {
  __builtin_amdgcn_global_load_lds((const GLOBAL_AS void*)g, (LDS_AS void*)l, 16, 0, 0);
}

// ---------------------------------------------------------------------------
// fp32 -> bf16 conversion (vectorized, grid-stride)
// ---------------------------------------------------------------------------
__global__ void f32_to_bf16_vec(const float* __restrict__ src,
                                unsigned short* __restrict__ dst, int n4) {
  int i = blockIdx.x * blockDim.x + threadIdx.x;
  int stride = gridDim.x * blockDim.x;
  for (; i < n4; i += stride) {
    float4 v = reinterpret_cast<const float4*>(src)[i];
    ushort4 o;
    o.x = f2b_rne(v.x); o.y = f2b_rne(v.y);
    o.z = f2b_rne(v.z); o.w = f2b_rne(v.w);
    reinterpret_cast<ushort4*>(dst)[i] = o;
  }
}

// ---------------------------------------------------------------------------
// V transpose: qkv V-block rows -> vt[bh][d][T], both sides coalesced via
// XOR-swizzled 64x64 LDS tile.  Grid (T/64, B*H).
// ---------------------------------------------------------------------------
__global__ __launch_bounds__(256)
void v_transpose(const unsigned short* __restrict__ qkv,
                 unsigned short* __restrict__ vt) {
  __shared__ __align__(16) unsigned short Ts[64][64];
  const int tc = blockIdx.x, bh = blockIdx.y;
  const int b = bh >> 4, hed = bh & 15;
  const int t0 = tc * 64;
  const int tid = threadIdx.x;
  {
    const int r = tid >> 2, cb = (tid & 3) * 2;  // row, chunk-pair
    const unsigned short* src =
        qkv + (size_t)(b * 2048 + t0 + r) * 3072 + 2048 + hed * 64;
    bf16x8 v0 = *(const bf16x8*)(src + cb * 8);
    bf16x8 v1 = *(const bf16x8*)(src + cb * 8 + 8);
    *(bf16x8*)&Ts[r][(cb ^ (r & 7)) * 8] = v0;
    *(bf16x8*)&Ts[r][((cb + 1) ^ (r & 7)) * 8] = v1;
  }
  __syncthreads();
  const int d = tid >> 2;
  unsigned short* dst = vt + ((size_t)bh * 64 + d) * 2048 + t0;
#pragma unroll
  for (int tb2 = 0; tb2 < 2; ++tb2) {
    int tb = (tid & 3) * 2 + tb2;
    union { unsigned short s[8]; bf16x8 v; } o;
#pragma unroll
    for (int i = 0; i < 8; ++i) {
      int row = tb * 8 + i;
      o.s[i] = Ts[row][(((d >> 3) ^ (row & 7)) * 8) + (d & 7)];
    }
    *(bf16x8*)(dst + tb * 8) = o.v;
  }
}

// ---------------------------------------------------------------------------
// NT GEMM: C[M,N] = A[M,K] * B[N,K]^T, bf16 in, fp32 acc. (vanilla stores)
// ---------------------------------------------------------------------------
template <int OUT_BF16>
__global__ __launch_bounds__(256)
void gemm_nt(const unsigned short* __restrict__ A,
             const unsigned short* __restrict__ B,
             void* __restrict__ Cout, int M, int N, int K) {
  __shared__ __align__(16) unsigned short As[128][32];
  __shared__ __align__(16) unsigned short Bs[128][32];
  const int tid = threadIdx.x;
  const int w = tid >> 6, lane = tid & 63;
  const int l16 = lane & 15, lg = lane >> 4;
  const int wrow = (w >> 1) * 64, wcol = (w & 1) * 64;
  const int m0 = blockIdx.y * 128, n0 = blockIdx.x * 128;

  f32x4 acc[4][4] = {};

  auto stage = [&](int k0) {
#pragma unroll
    for (int c2 = 0; c2 < 2; ++c2) {
      int c = 2 * w + c2;
      const unsigned short* ga =
          A + (size_t)(m0 + 16 * c + (lane >> 2)) * K + k0 + (lane & 3) * 8;
      gload_lds16(ga, &As[16 * c][0]);
      const unsigned short* gb =
          B + (size_t)(n0 + 16 * c + (lane >> 2)) * K + k0 + (lane & 3) * 8;
      gload_lds16(gb, &Bs[16 * c][0]);
    }
  };

  stage(0);
  __syncthreads();
  const int nk = K >> 5;
  for (int ks = 0; ks < nk; ++ks) {
    bf16x8 af[4], bfr[4];
#pragma unroll
    for (int mi = 0; mi < 4; ++mi)
      af[mi] = *(const bf16x8*)&As[wrow + mi * 16 + l16][lg * 8];
#pragma unroll
    for (int ni = 0; ni < 4; ++ni)
      bfr[ni] = *(const bf16x8*)&Bs[wcol + ni * 16 + l16][lg * 8];
    __syncthreads();
    if (ks + 1 < nk) stage((ks + 1) * 32);
#pragma unroll
    for (int mi = 0; mi < 4; ++mi)
#pragma unroll
      for (int ni = 0; ni < 4; ++ni)
        acc[mi][ni] = __builtin_amdgcn_mfma_f32_16x16x32_bf16(
            af[mi], bfr[ni], acc[mi][ni], 0, 0, 0);
    __syncthreads();
  }

#pragma unroll
  for (int mi = 0; mi < 4; ++mi) {
#pragma unroll
    for (int ni = 0; ni < 4; ++ni) {
#pragma unroll
      for (int j = 0; j < 4; ++j) {
        int row = m0 + wrow + mi * 16 + lg * 4 + j;
        int col = n0 + wcol + ni * 16 + l16;
        if (OUT_BF16) {
          ((unsigned short*)Cout)[(size_t)row * N + col] =
              f2b_rne(acc[mi][ni][j]);
        } else {
          ((float*)Cout)[(size_t)row * N + col] = acc[mi][ni][j];
        }
      }
    }
  }
}

// ---------------------------------------------------------------------------
// Flash attention fwd, causal; swapped-QK^T 32x32 structure.
// Block: 4 waves x 32 q-rows = 128 q. KV tile 64, double-buffered; K and V^T
// staged via global_load_lds with XOR-swizzled source. One barrier per tile.
// qt remap: pair-interleaved [15,0,14,1,...] so contiguous 4-block groups
// (one CU's residency) get equal total work (68 tile-units).
// ---------------------------------------------------------------------------
__global__ __launch_bounds__(256)
void attn_fwd(const unsigned short* __restrict__ qkv,
              const unsigned short* __restrict__ vt,
              unsigned short* __restrict__ out) {
  const int T = 2048, C3 = 3072;
  __shared__ __align__(16) unsigned short Ks[2][64][64];  // [kv][d] swizzled
  __shared__ __align__(16) unsigned short Vs[2][64][64];  // [d][kv] swizzled
  __shared__ float Bc[4][32];                             // per-wave broadcast

  const int tid = threadIdx.x, w = tid >> 6, lane = tid & 63;
  const int l31 = lane & 31, h = lane >> 5;
  // XCD swizzle: 1024 blocks = 8 XCDs x 128; qt pair-interleaved balanced.
  const int wgid = (blockIdx.x & 7) * 128 + (blockIdx.x >> 3);
  const int qidx = wgid & 15;
  const int qt = (qidx & 1) ? (qidx >> 1) : (15 - (qidx >> 1));
  const int bh = wgid >> 4;
  const int b = bh >> 4, hed = bh & 15;
  const int qw = qt * 128 + w * 32;
  const size_t rowbase = (size_t)b * T * C3;
  const int hoff = hed * 64;
  const unsigned short* vbase = vt + (size_t)bh * 64 * 2048;
  const float c2 = 0.18033688f;  // 0.125 * log2(e)

  auto stageK = [&](int kv0, int buf) {
#pragma unroll
    for (int pp = 0; pp < 2; ++pp) {
      int chunk = w * 2 + pp;
      int row = chunk * 8 + (lane >> 3);
      int blk = (lane & 7) ^ (lane >> 3);
      gload_lds16(
          qkv + rowbase + (size_t)(kv0 + row) * C3 + 1024 + hoff + blk * 8,
          &Ks[buf][chunk * 8][0]);
    }
  };
  auto stageV = [&](int kv0, int buf) {
#pragma unroll
    for (int pp = 0; pp < 2; ++pp) {
      int chunk = w * 2 + pp;
      int drow = chunk * 8 + (lane >> 3);
      int blk = (lane & 7) ^ (lane >> 3);
      gload_lds16(vbase + (size_t)drow * 2048 + kv0 + blk * 8,
                  &Vs[buf][chunk * 8][0]);
    }
  };

  // Q as B-operand frags: qf[s] = Q[qw + l31][hoff + 16s + 8h .. +8)
  bf16x8 qf[4];
  {
    const unsigned short* qp =
        qkv + rowbase + (size_t)(qw + l31) * C3 + hoff + h * 8;
#pragma unroll
    for (int s = 0; s < 4; ++s) qf[s] = *(const bf16x8*)(qp + 16 * s);
  }

  f32x16 oacc[2] = {};  // O: col d = 32dt + l31, rows q spread over regs
  float m_r = -1e30f, sum = 0.f;

  stageK(0, 0);
  stageV(0, 0);
  __syncthreads();

  int cur = 0;
  const int ntiles = qt * 2 + 2;
  for (int t = 0; t < ntiles; ++t) {
    const int kv0 = t * 64;
    if (t + 1 < ntiles) {  // issue next-tile loads early (fly under compute)
      stageK(kv0 + 64, cur ^ 1);
      stageV(kv0 + 64, cur ^ 1);
    }

    if (kv0 <= qw) {  // wave-uniform causal participation
      // ---- S^T = K Q^T : sacc[kt] rows kv = 32kt + (r&3)+8(r>>2)+4h ----
      f32x16 sacc[2] = {};
      __builtin_amdgcn_s_setprio(1);
#pragma unroll
      for (int s = 0; s < 4; ++s) {
#pragma unroll
        for (int kt = 0; kt < 2; ++kt) {
          int row = kt * 32 + l31;
          int blk = (2 * s + h) ^ (row & 7);
          bf16x8 kf = *(const bf16x8*)&Ks[cur][row][blk * 8];
          sacc[kt] = __builtin_amdgcn_mfma_f32_32x32x16_bf16(kf, qf[s],
                                                             sacc[kt], 0, 0, 0);
        }
      }
      __builtin_amdgcn_s_setprio(0);
      // ---- causal mask (diagonal tiles only) ----
      if (kv0 + 64 > qw) {
        int q_abs = qw + l31;
#pragma unroll
        for (int kt = 0; kt < 2; ++kt)
#pragma unroll
          for (int r = 0; r < 16; ++r) {
            int kv_abs = kv0 + kt * 32 + (r & 3) + 8 * (r >> 2) + 4 * h;
            if (kv_abs > q_abs) sacc[kt][r] = -1e30f;
          }
      }
      // ---- tile max: 3-level tree + one partner shfl ----
      float mx[8];
#pragma unroll
      for (int g = 0; g < 8; ++g)
        mx[g] = fmaxf(fmaxf(sacc[g >> 2][(g & 3) * 4 + 0],
                            sacc[g >> 2][(g & 3) * 4 + 1]),
                      fmaxf(sacc[g >> 2][(g & 3) * 4 + 2],
                            sacc[g >> 2][(g & 3) * 4 + 3]));
      float tm = fmaxf(fmaxf(fmaxf(mx[0], mx[1]), fmaxf(mx[2], mx[3])),
                       fmaxf(fmaxf(mx[4], mx[5]), fmaxf(mx[6], mx[7])));
      tm = fmaxf(tm, __shfl_xor(tm, 32));
      if (t == 0) {
        m_r = tm;
      } else if (!__all(tm <= m_r + 16.0f)) {
        float mnew = fmaxf(m_r, tm);
        float corr = __builtin_amdgcn_exp2f((m_r - mnew) * c2);
        sum *= corr;
        if (h == 0) Bc[w][l31] = corr;
        m_r = mnew;
        asm volatile("s_waitcnt lgkmcnt(0)" ::: "memory");
#pragma unroll
        for (int r = 0; r < 16; ++r) {
          float cr = Bc[w][(r & 3) + 8 * (r >> 2) + 4 * h];
          oacc[0][r] *= cr;
          oacc[1][r] *= cr;
        }
      }
      // ---- P = exp2(c2*(s - m)), in-register; accumulate sum ----
      float m2 = m_r * c2;
      float s0 = 0.f, s1 = 0.f, s2 = 0.f, s3 = 0.f;
#pragma unroll
      for (int kt = 0; kt < 2; ++kt)
#pragma unroll
        for (int r = 0; r < 16; r += 4) {
          float p0 = __builtin_amdgcn_exp2f(fmaf(sacc[kt][r + 0], c2, -m2));
          float p1 = __builtin_amdgcn_exp2f(fmaf(sacc[kt][r + 1], c2, -m2));
          float p2 = __builtin_amdgcn_exp2f(fmaf(sacc[kt][r + 2], c2, -m2));
          float p3 = __builtin_amdgcn_exp2f(fmaf(sacc[kt][r + 3], c2, -m2));
          sacc[kt][r + 0] = p0; sacc[kt][r + 1] = p1;
          sacc[kt][r + 2] = p2; sacc[kt][r + 3] = p3;
          s0 += p0; s1 += p1; s2 += p2; s3 += p3;
        }
      float sl = (s0 + s1) + (s2 + s3);
      sum += sl + __shfl_xor(sl, 32);
      // ---- pack P pairs to bf16 ----
      unsigned pk[16];
#pragma unroll
      for (int kt = 0; kt < 2; ++kt)
#pragma unroll
        for (int r = 0; r < 16; r += 2)
          pk[kt * 8 + (r >> 1)] = cvt_pk_bf16(sacc[kt][r], sacc[kt][r + 1]);
      // ---- PV: A-frags via permlane32_swap (half-exchange), accumulate ----
      __builtin_amdgcn_s_setprio(1);
#pragma unroll
      for (int sg = 0; sg < 4; ++sg) {
        const int kt = sg >> 1, s = sg & 1;
        const int base = kt * 8 + 4 * s;
        uint2v r02 = __builtin_amdgcn_permlane32_swap(pk[base], pk[base + 2],
                                                      false, false);
        uint2v r13 = __builtin_amdgcn_permlane32_swap(pk[base + 1], pk[base + 3],
                                                      false, false);
        union { unsigned u[4]; bf16x8 v; } A;
        A.u[0] = r02.x; A.u[1] = r13.x;
        A.u[2] = r02.y; A.u[3] = r13.y;
#pragma unroll
        for (int dt = 0; dt < 2; ++dt) {
          int d = dt * 32 + l31;
          int blk = (2 * sg + h) ^ (d & 7);
          bf16x8 vf = *(const bf16x8*)&Vs[cur][d][blk * 8];
          oacc[dt] = __builtin_amdgcn_mfma_f32_32x32x16_bf16(A.v, vf,
                                                             oacc[dt], 0, 0, 0);
        }
      }
      __builtin_amdgcn_s_setprio(0);
    }

    __syncthreads();  // staged tile ready; prev reads done
    cur ^= 1;
  }

  // ---- epilogue: broadcast 1/sum[q] to O-layout, store bf16 ----
  if (h == 0) Bc[w][l31] = 1.0f / sum;
  asm volatile("s_waitcnt lgkmcnt(0)" ::: "memory");
#pragma unroll
  for (int r = 0; r < 16; ++r) {
    int ql = (r & 3) + 8 * (r >> 2) + 4 * h;
    float inv = Bc[w][ql];
    int q_abs = qw + ql;
#pragma unroll
    for (int dt = 0; dt < 2; ++dt) {
      out[(size_t)(b * T + q_abs) * 1024 + hoff + dt * 32 + l31] =
          f2b_rne(oacc[dt][r] * inv);
    }
  }
}

// ---------------------------------------------------------------------------
extern "C" void kernel_launch(void* const* d_in, const int* in_sizes, int n_in,
                              void* d_out, int out_size, void* d_ws,
                              size_t ws_size, hipStream_t stream) {
  const float* x = (const float*)d_in[0];      // [4,2048,1024]
  const float* w_qkv = (const float*)d_in[1];  // [3072,1024]
  const float* w_out = (const float*)d_in[2];  // [1024,1024]
  float* out = (float*)d_out;                  // [4,2048,1024] fp32

  const int M = 8192, C = 1024, C3 = 3072;

  unsigned short* xb = (unsigned short*)d_ws;      // M*C  (reused as attno)
  unsigned short* wqkvb = xb + (size_t)M * C;      // C3*C
  unsigned short* woutb = wqkvb + (size_t)C3 * C;  // C*C
  unsigned short* qkv = woutb + (size_t)C * C;     // M*C3
  unsigned short* vtb = qkv + (size_t)M * C3;      // B*H*64*T = M*C
  unsigned short* attno = xb;                      // alias: xb dead post-GEMM1

  f32_to_bf16_vec<<<1024, 256, 0, stream>>>(x, xb, M * C / 4);
  f32_to_bf16_vec<<<512, 256, 0, stream>>>(w_qkv, wqkvb, C3 * C / 4);
  f32_to_bf16_vec<<<256, 256, 0, stream>>>(w_out, woutb, C * C / 4);

  gemm_nt<1><<<dim3(C3 / 128, M / 128), 256, 0, stream>>>(xb, wqkvb, qkv,
                                                          M, C3, C);

  v_transpose<<<dim3(32, 64), 256, 0, stream>>>(qkv, vtb);

  attn_fwd<<<1024, 256, 0, stream>>>(qkv, vtb, attno);

  gemm_nt<0><<<dim3(C / 128, M / 128), 256, 0, stream>>>(attno, woutb, out,
                                                         M, C, C);
}

// Round 9
// 211.057 us; speedup vs baseline: 1.1396x; 1.0539x over previous
//
#include <hip/hip_runtime.h>
#include <hip/hip_bf16.h>

// ---------------------------------------------------------------------------
// Fused causal MHA forward: x[B,T,C] fp32, w_qkv[3C,C] fp32, w_out[C,C] fp32
// B=4 T=2048 C=1024 H=16 hd=64.  All matmuls in bf16 MFMA, fp32 accumulate.
// convert->bf16 | GEMM qkv | V-transpose | flash-attn | GEMM out-proj.
// ---------------------------------------------------------------------------

typedef __attribute__((ext_vector_type(8))) short bf16x8;
typedef __attribute__((ext_vector_type(4))) float f32x4;
typedef __attribute__((ext_vector_type(16))) float f32x16;
typedef __attribute__((ext_vector_type(2))) unsigned uint2v;

#define GLOBAL_AS __attribute__((address_space(1)))
#define LDS_AS __attribute__((address_space(3)))

__device__ __forceinline__ unsigned short f2b_rne(float f) {
  unsigned u = __float_as_uint(f);
  unsigned r = u + 0x7fffu + ((u >> 16) & 1u);
  return (unsigned short)(r >> 16);
}

__device__ __forceinline__ unsigned cvt_pk_bf16(float lo, float hi) {
  unsigned r;
  asm("v_cvt_pk_bf16_f32 %0, %1, %2" : "=v"(r) : "v"(lo), "v"(hi));
  return r;
}

__device__ __forceinline__ void gload_lds16(const void* g, void* l) {
  __builtin_amdgcn_global_load_lds((const GLOBAL_AS void*)g, (LDS_AS void*)l, 16, 0, 0);
}

// ---------------------------------------------------------------------------
// fp32 -> bf16 conversion (vectorized, grid-stride)
// ---------------------------------------------------------------------------
__global__ void f32_to_bf16_vec(const float* __restrict__ src,
                                unsigned short* __restrict__ dst, int n4) {
  int i = blockIdx.x * blockDim.x + threadIdx.x;
  int stride = gridDim.x * blockDim.x;
  for (; i < n4; i += stride) {
    float4 v = reinterpret_cast<const float4*>(src)[i];
    ushort4 o;
    o.x = f2b_rne(v.x); o.y = f2b_rne(v.y);
    o.z = f2b_rne(v.z); o.w = f2b_rne(v.w);
    reinterpret_cast<ushort4*>(dst)[i] = o;
  }
}

// ---------------------------------------------------------------------------
// V transpose: qkv V-block rows -> vt[bh][d][T], both sides coalesced via
// XOR-swizzled 64x64 LDS tile.  Grid (T/64, B*H).
// ---------------------------------------------------------------------------
__global__ __launch_bounds__(256)
void v_transpose(const unsigned short* __restrict__ qkv,
                 unsigned short* __restrict__ vt) {
  __shared__ __align__(16) unsigned short Ts[64][64];
  const int tc = blockIdx.x, bh = blockIdx.y;
  const int b = bh >> 4, hed = bh & 15;
  const int t0 = tc * 64;
  const int tid = threadIdx.x;
  {
    const int r = tid >> 2, cb = (tid & 3) * 2;  // row, chunk-pair
    const unsigned short* src =
        qkv + (size_t)(b * 2048 + t0 + r) * 3072 + 2048 + hed * 64;
    bf16x8 v0 = *(const bf16x8*)(src + cb * 8);
    bf16x8 v1 = *(const bf16x8*)(src + cb * 8 + 8);
    *(bf16x8*)&Ts[r][(cb ^ (r & 7)) * 8] = v0;
    *(bf16x8*)&Ts[r][((cb + 1) ^ (r & 7)) * 8] = v1;
  }
  __syncthreads();
  const int d = tid >> 2;
  unsigned short* dst = vt + ((size_t)bh * 64 + d) * 2048 + t0;
#pragma unroll
  for (int tb2 = 0; tb2 < 2; ++tb2) {
    int tb = (tid & 3) * 2 + tb2;
    union { unsigned short s[8]; bf16x8 v; } o;
#pragma unroll
    for (int i = 0; i < 8; ++i) {
      int row = tb * 8 + i;
      o.s[i] = Ts[row][(((d >> 3) ^ (row & 7)) * 8) + (d & 7)];
    }
    *(bf16x8*)(dst + tb * 8) = o.v;
  }
}

// ---------------------------------------------------------------------------
// NT GEMM: C[M,N] = A[M,K] * B[N,K]^T, bf16 in, fp32 acc.
// ---------------------------------------------------------------------------
template <int OUT_BF16>
__global__ __launch_bounds__(256)
void gemm_nt(const unsigned short* __restrict__ A,
             const unsigned short* __restrict__ B,
             void* __restrict__ Cout, int M, int N, int K) {
  __shared__ __align__(16) unsigned short As[128][32];
  __shared__ __align__(16) unsigned short Bs[128][32];
  const int tid = threadIdx.x;
  const int w = tid >> 6, lane = tid & 63;
  const int l16 = lane & 15, lg = lane >> 4;
  const int wrow = (w >> 1) * 64, wcol = (w & 1) * 64;
  const int m0 = blockIdx.y * 128, n0 = blockIdx.x * 128;

  f32x4 acc[4][4] = {};

  auto stage = [&](int k0) {
#pragma unroll
    for (int c2 = 0; c2 < 2; ++c2) {
      int c = 2 * w + c2;
      const unsigned short* ga =
          A + (size_t)(m0 + 16 * c + (lane >> 2)) * K + k0 + (lane & 3) * 8;
      gload_lds16(ga, &As[16 * c][0]);
      const unsigned short* gb =
          B + (size_t)(n0 + 16 * c + (lane >> 2)) * K + k0 + (lane & 3) * 8;
      gload_lds16(gb, &Bs[16 * c][0]);
    }
  };

  stage(0);
  __syncthreads();
  const int nk = K >> 5;
  for (int ks = 0; ks < nk; ++ks) {
    bf16x8 af[4], bfr[4];
#pragma unroll
    for (int mi = 0; mi < 4; ++mi)
      af[mi] = *(const bf16x8*)&As[wrow + mi * 16 + l16][lg * 8];
#pragma unroll
    for (int ni = 0; ni < 4; ++ni)
      bfr[ni] = *(const bf16x8*)&Bs[wcol + ni * 16 + l16][lg * 8];
    __syncthreads();
    if (ks + 1 < nk) stage((ks + 1) * 32);
#pragma unroll
    for (int mi = 0; mi < 4; ++mi)
#pragma unroll
      for (int ni = 0; ni < 4; ++ni)
        acc[mi][ni] = __builtin_amdgcn_mfma_f32_16x16x32_bf16(
            af[mi], bfr[ni], acc[mi][ni], 0, 0, 0);
    __syncthreads();
  }

#pragma unroll
  for (int mi = 0; mi < 4; ++mi) {
#pragma unroll
    for (int ni = 0; ni < 4; ++ni) {
#pragma unroll
      for (int j = 0; j < 4; ++j) {
        int row = m0 + wrow + mi * 16 + lg * 4 + j;
        int col = n0 + wcol + ni * 16 + l16;
        if (OUT_BF16) {
          ((unsigned short*)Cout)[(size_t)row * N + col] =
              f2b_rne(acc[mi][ni][j]);
        } else {
          ((float*)Cout)[(size_t)row * N + col] = acc[mi][ni][j];
        }
      }
    }
  }
}

// ---------------------------------------------------------------------------
// Flash attention fwd, causal; swapped-QK^T 32x32 structure.
// Block: 4 waves x 32 q-rows = 128 q. KV tile 64, double-buffered; K and V^T
// staged via global_load_lds with XOR-swizzled source.
// T4 counted-vmcnt pipeline: raw s_barrier pair per tile, s_waitcnt vmcnt(4)
// (never 0 mid-loop) so prefetch loads stay in flight across barriers.
// ---------------------------------------------------------------------------
__global__ __launch_bounds__(256)
void attn_fwd(const unsigned short* __restrict__ qkv,
              const unsigned short* __restrict__ vt,
              unsigned short* __restrict__ out) {
  const int T = 2048, C3 = 3072;
  __shared__ __align__(16) unsigned short Ks[2][64][64];  // [kv][d] swizzled
  __shared__ __align__(16) unsigned short Vs[2][64][64];  // [d][kv] swizzled
  __shared__ float Bc[4][32];                             // per-wave broadcast

  const int tid = threadIdx.x, w = tid >> 6, lane = tid & 63;
  const int l31 = lane & 31, h = lane >> 5;
  // XCD swizzle: 1024 blocks = 8 XCDs x 128; qt descending (heavy first).
  const int wgid = (blockIdx.x & 7) * 128 + (blockIdx.x >> 3);
  const int qt = 15 - (wgid & 15);
  const int bh = wgid >> 4;
  const int b = bh >> 4, hed = bh & 15;
  const int qw = qt * 128 + w * 32;
  const size_t rowbase = (size_t)b * T * C3;
  const int hoff = hed * 64;
  const unsigned short* vbase = vt + (size_t)bh * 64 * 2048;
  const float c2 = 0.18033688f;  // 0.125 * log2(e)

  auto stageK = [&](int kv0, int buf) {
#pragma unroll
    for (int pp = 0; pp < 2; ++pp) {
      int chunk = w * 2 + pp;
      int row = chunk * 8 + (lane >> 3);
      int blk = (lane & 7) ^ (lane >> 3);
      gload_lds16(
          qkv + rowbase + (size_t)(kv0 + row) * C3 + 1024 + hoff + blk * 8,
          &Ks[buf][chunk * 8][0]);
    }
  };
  auto stageV = [&](int kv0, int buf) {
#pragma unroll
    for (int pp = 0; pp < 2; ++pp) {
      int chunk = w * 2 + pp;
      int drow = chunk * 8 + (lane >> 3);
      int blk = (lane & 7) ^ (lane >> 3);
      gload_lds16(vbase + (size_t)drow * 2048 + kv0 + blk * 8,
                  &Vs[buf][chunk * 8][0]);
    }
  };

  // Q as B-operand frags: qf[s] = Q[qw + l31][hoff + 16s + 8h .. +8)
  bf16x8 qf[4];
  {
    const unsigned short* qp =
        qkv + rowbase + (size_t)(qw + l31) * C3 + hoff + h * 8;
#pragma unroll
    for (int s = 0; s < 4; ++s) qf[s] = *(const bf16x8*)(qp + 16 * s);
  }

  f32x16 oacc[2] = {};  // O: col d = 32dt + l31, rows q spread over regs
  float m_r = -1e30f, sum = 0.f;

  stageK(0, 0);
  stageV(0, 0);

  int cur = 0;
  const int ntiles = qt * 2 + 2;
  for (int t = 0; t < ntiles; ++t) {
    const int kv0 = t * 64;
    // barrier A: all waves done reading buf[cur^1] (iter t-1's reads)
    __builtin_amdgcn_s_barrier();
    if (t + 1 < ntiles) {  // issue next-tile loads; keep them in flight
      stageK(kv0 + 64, cur ^ 1);
      stageV(kv0 + 64, cur ^ 1);
      asm volatile("s_waitcnt vmcnt(4)" ::: "memory");  // loads(t) done
    } else {
      asm volatile("s_waitcnt vmcnt(0)" ::: "memory");
    }
    // barrier B: every wave's loads(t) have landed in LDS
    __builtin_amdgcn_s_barrier();
    __builtin_amdgcn_sched_barrier(0);

    if (kv0 <= qw) {  // wave-uniform causal participation
      // ---- S^T = K Q^T : sacc[kt] rows kv = 32kt + (r&3)+8(r>>2)+4h ----
      f32x16 sacc[2] = {};
      __builtin_amdgcn_s_setprio(1);
#pragma unroll
      for (int s = 0; s < 4; ++s) {
#pragma unroll
        for (int kt = 0; kt < 2; ++kt) {
          int row = kt * 32 + l31;
          int blk = (2 * s + h) ^ (row & 7);
          bf16x8 kf = *(const bf16x8*)&Ks[cur][row][blk * 8];
          sacc[kt] = __builtin_amdgcn_mfma_f32_32x32x16_bf16(kf, qf[s],
                                                             sacc[kt], 0, 0, 0);
        }
      }
      __builtin_amdgcn_s_setprio(0);
      // ---- causal mask (diagonal tiles only) ----
      if (kv0 + 64 > qw) {
        int q_abs = qw + l31;
#pragma unroll
        for (int kt = 0; kt < 2; ++kt)
#pragma unroll
          for (int r = 0; r < 16; ++r) {
            int kv_abs = kv0 + kt * 32 + (r & 3) + 8 * (r >> 2) + 4 * h;
            if (kv_abs > q_abs) sacc[kt][r] = -1e30f;
          }
      }
      // ---- tile max: 3-level tree + one partner shfl ----
      float mx[8];
#pragma unroll
      for (int g = 0; g < 8; ++g)
        mx[g] = fmaxf(fmaxf(sacc[g >> 2][(g & 3) * 4 + 0],
                            sacc[g >> 2][(g & 3) * 4 + 1]),
                      fmaxf(sacc[g >> 2][(g & 3) * 4 + 2],
                            sacc[g >> 2][(g & 3) * 4 + 3]));
      float tm = fmaxf(fmaxf(fmaxf(mx[0], mx[1]), fmaxf(mx[2], mx[3])),
                       fmaxf(fmaxf(mx[4], mx[5]), fmaxf(mx[6], mx[7])));
      tm = fmaxf(tm, __shfl_xor(tm, 32));
      if (t == 0) {
        m_r = tm;
      } else if (!__all(tm <= m_r + 16.0f)) {
        float mnew = fmaxf(m_r, tm);
        float corr = __builtin_amdgcn_exp2f((m_r - mnew) * c2);
        sum *= corr;
        if (h == 0) Bc[w][l31] = corr;
        m_r = mnew;
        asm volatile("s_waitcnt lgkmcnt(0)" ::: "memory");
#pragma unroll
        for (int r = 0; r < 16; ++r) {
          float cr = Bc[w][(r & 3) + 8 * (r >> 2) + 4 * h];
          oacc[0][r] *= cr;
          oacc[1][r] *= cr;
        }
      }
      // ---- P = exp2(c2*(s - m)), in-register; accumulate sum ----
      float m2 = m_r * c2;
      float s0 = 0.f, s1 = 0.f, s2 = 0.f, s3 = 0.f;
#pragma unroll
      for (int kt = 0; kt < 2; ++kt)
#pragma unroll
        for (int r = 0; r < 16; r += 4) {
          float p0 = __builtin_amdgcn_exp2f(fmaf(sacc[kt][r + 0], c2, -m2));
          float p1 = __builtin_amdgcn_exp2f(fmaf(sacc[kt][r + 1], c2, -m2));
          float p2 = __builtin_amdgcn_exp2f(fmaf(sacc[kt][r + 2], c2, -m2));
          float p3 = __builtin_amdgcn_exp2f(fmaf(sacc[kt][r + 3], c2, -m2));
          sacc[kt][r + 0] = p0; sacc[kt][r + 1] = p1;
          sacc[kt][r + 2] = p2; sacc[kt][r + 3] = p3;
          s0 += p0; s1 += p1; s2 += p2; s3 += p3;
        }
      float sl = (s0 + s1) + (s2 + s3);
      sum += sl + __shfl_xor(sl, 32);
      // ---- pack P pairs to bf16 ----
      unsigned pk[16];
#pragma unroll
      for (int kt = 0; kt < 2; ++kt)
#pragma unroll
        for (int r = 0; r < 16; r += 2)
          pk[kt * 8 + (r >> 1)] = cvt_pk_bf16(sacc[kt][r], sacc[kt][r + 1]);
      // ---- PV: A-frags via permlane32_swap (half-exchange), accumulate ----
      __builtin_amdgcn_s_setprio(1);
#pragma unroll
      for (int sg = 0; sg < 4; ++sg) {
        const int kt = sg >> 1, s = sg & 1;
        const int base = kt * 8 + 4 * s;
        uint2v r02 = __builtin_amdgcn_permlane32_swap(pk[base], pk[base + 2],
                                                      false, false);
        uint2v r13 = __builtin_amdgcn_permlane32_swap(pk[base + 1], pk[base + 3],
                                                      false, false);
        union { unsigned u[4]; bf16x8 v; } A;
        A.u[0] = r02.x; A.u[1] = r13.x;
        A.u[2] = r02.y; A.u[3] = r13.y;
#pragma unroll
        for (int dt = 0; dt < 2; ++dt) {
          int d = dt * 32 + l31;
          int blk = (2 * sg + h) ^ (d & 7);
          bf16x8 vf = *(const bf16x8*)&Vs[cur][d][blk * 8];
          oacc[dt] = __builtin_amdgcn_mfma_f32_32x32x16_bf16(A.v, vf,
                                                             oacc[dt], 0, 0, 0);
        }
      }
      __builtin_amdgcn_s_setprio(0);
    }
    cur ^= 1;
  }

  // ---- epilogue: broadcast 1/sum[q] to O-layout, store bf16 ----
  if (h == 0) Bc[w][l31] = 1.0f / sum;
  asm volatile("s_waitcnt lgkmcnt(0)" ::: "memory");
#pragma unroll
  for (int r = 0; r < 16; ++r) {
    int ql = (r & 3) + 8 * (r >> 2) + 4 * h;
    float inv = Bc[w][ql];
    int q_abs = qw + ql;
#pragma unroll
    for (int dt = 0; dt < 2; ++dt) {
      out[(size_t)(b * T + q_abs) * 1024 + hoff + dt * 32 + l31] =
          f2b_rne(oacc[dt][r] * inv);
    }
  }
}

// ---------------------------------------------------------------------------
extern "C" void kernel_launch(void* const* d_in, const int* in_sizes, int n_in,
                              void* d_out, int out_size, void* d_ws,
                              size_t ws_size, hipStream_t stream) {
  const float* x = (const float*)d_in[0];      // [4,2048,1024]
  const float* w_qkv = (const float*)d_in[1];  // [3072,1024]
  const float* w_out = (const float*)d_in[2];  // [1024,1024]
  float* out = (float*)d_out;                  // [4,2048,1024] fp32

  const int M = 8192, C = 1024, C3 = 3072;

  unsigned short* xb = (unsigned short*)d_ws;      // M*C  (reused as attno)
  unsigned short* wqkvb = xb + (size_t)M * C;      // C3*C
  unsigned short* woutb = wqkvb + (size_t)C3 * C;  // C*C
  unsigned short* qkv = woutb + (size_t)C * C;     // M*C3
  unsigned short* vtb = qkv + (size_t)M * C3;      // B*H*64*T = M*C
  unsigned short* attno = xb;                      // alias: xb dead post-GEMM1

  f32_to_bf16_vec<<<1024, 256, 0, stream>>>(x, xb, M * C / 4);
  f32_to_bf16_vec<<<512, 256, 0, stream>>>(w_qkv, wqkvb, C3 * C / 4);
  f32_to_bf16_vec<<<256, 256, 0, stream>>>(w_out, woutb, C * C / 4);

  gemm_nt<1><<<dim3(C3 / 128, M / 128), 256, 0, stream>>>(xb, wqkvb, qkv,
                                                          M, C3, C);

  v_transpose<<<dim3(32, 64), 256, 0, stream>>>(qkv, vtb);

  attn_fwd<<<1024, 256, 0, stream>>>(qkv, vtb, attno);

  gemm_nt<0><<<dim3(C / 128, M / 128), 256, 0, stream>>>(attno, woutb, out,
                                                         M, C, C);
}

// Round 10
// 203.463 us; speedup vs baseline: 1.1821x; 1.0373x over previous
//
#include <hip/hip_runtime.h>
#include <hip/hip_bf16.h>

// ---------------------------------------------------------------------------
// Fused causal MHA forward: x[B,T,C] fp32, w_qkv[3C,C] fp32, w_out[C,C] fp32
// B=4 T=2048 C=1024 H=16 hd=64.  All matmuls in bf16 MFMA, fp32 accumulate.
// convert->bf16 | GEMM qkv (256x128 mfma32) | V-transpose | flash-attn | proj.
// ---------------------------------------------------------------------------

typedef __attribute__((ext_vector_type(8))) short bf16x8;
typedef __attribute__((ext_vector_type(4))) float f32x4;
typedef __attribute__((ext_vector_type(16))) float f32x16;
typedef __attribute__((ext_vector_type(2))) unsigned uint2v;

#define GLOBAL_AS __attribute__((address_space(1)))
#define LDS_AS __attribute__((address_space(3)))

__device__ __forceinline__ unsigned short f2b_rne(float f) {
  unsigned u = __float_as_uint(f);
  unsigned r = u + 0x7fffu + ((u >> 16) & 1u);
  return (unsigned short)(r >> 16);
}

__device__ __forceinline__ unsigned cvt_pk_bf16(float lo, float hi) {
  unsigned r;
  asm("v_cvt_pk_bf16_f32 %0, %1, %2" : "=v"(r) : "v"(lo), "v"(hi));
  return r;
}

__device__ __forceinline__ void gload_lds16(const void* g, void* l) {
  __builtin_amdgcn_global_load_lds((const GLOBAL_AS void*)g, (LDS_AS void*)l, 16, 0, 0);
}

// ---------------------------------------------------------------------------
// fp32 -> bf16 conversion (vectorized, grid-stride)
// ---------------------------------------------------------------------------
__global__ void f32_to_bf16_vec(const float* __restrict__ src,
                                unsigned short* __restrict__ dst, int n4) {
  int i = blockIdx.x * blockDim.x + threadIdx.x;
  int stride = gridDim.x * blockDim.x;
  for (; i < n4; i += stride) {
    float4 v = reinterpret_cast<const float4*>(src)[i];
    ushort4 o;
    o.x = f2b_rne(v.x); o.y = f2b_rne(v.y);
    o.z = f2b_rne(v.z); o.w = f2b_rne(v.w);
    reinterpret_cast<ushort4*>(dst)[i] = o;
  }
}

// ---------------------------------------------------------------------------
// V transpose: qkv V-block rows -> vt[bh][d][T], both sides coalesced via
// XOR-swizzled 64x64 LDS tile.  Grid (T/64, B*H).
// ---------------------------------------------------------------------------
__global__ __launch_bounds__(256)
void v_transpose(const unsigned short* __restrict__ qkv,
                 unsigned short* __restrict__ vt) {
  __shared__ __align__(16) unsigned short Ts[64][64];
  const int tc = blockIdx.x, bh = blockIdx.y;
  const int b = bh >> 4, hed = bh & 15;
  const int t0 = tc * 64;
  const int tid = threadIdx.x;
  {
    const int r = tid >> 2, cb = (tid & 3) * 2;  // row, chunk-pair
    const unsigned short* src =
        qkv + (size_t)(b * 2048 + t0 + r) * 3072 + 2048 + hed * 64;
    bf16x8 v0 = *(const bf16x8*)(src + cb * 8);
    bf16x8 v1 = *(const bf16x8*)(src + cb * 8 + 8);
    *(bf16x8*)&Ts[r][(cb ^ (r & 7)) * 8] = v0;
    *(bf16x8*)&Ts[r][((cb + 1) ^ (r & 7)) * 8] = v1;
  }
  __syncthreads();
  const int d = tid >> 2;
  unsigned short* dst = vt + ((size_t)bh * 64 + d) * 2048 + t0;
#pragma unroll
  for (int tb2 = 0; tb2 < 2; ++tb2) {
    int tb = (tid & 3) * 2 + tb2;
    union { unsigned short s[8]; bf16x8 v; } o;
#pragma unroll
    for (int i = 0; i < 8; ++i) {
      int row = tb * 8 + i;
      o.s[i] = Ts[row][(((d >> 3) ^ (row & 7)) * 8) + (d & 7)];
    }
    *(bf16x8*)(dst + tb * 8) = o.v;
  }
}

// ---------------------------------------------------------------------------
// QKV GEMM: qkv[M,3072] = xb[M,1024] * wqkv[3072,1024]^T, bf16 out.
// 256x128 tile, 8 waves (4Mx2N), BK=64, mfma_32x32x16.  Staging issued at
// tile start (full-tile latency cover), chunk-XOR swizzled LDS (conflict-
// light b128 reads), raw-barrier loop, bijective XCD swizzle (768 wg).
// ---------------------------------------------------------------------------
__global__ __launch_bounds__(512, 2)
void gemm_qkv(const unsigned short* __restrict__ A,   // [8192][1024]
              const unsigned short* __restrict__ B,   // [3072][1024]
              unsigned short* __restrict__ C) {       // [8192][3072]
  const int K = 1024, N = 3072;
  __shared__ __align__(16) unsigned short As[2][2][128 * 64];  // [buf][half]
  __shared__ __align__(16) unsigned short Bs[2][128 * 64];     // [buf]

  const int tid = threadIdx.x, wid = tid >> 6, lane = tid & 63;
  const int l31 = lane & 31, h = lane >> 5;
  // XCD swizzle: 768 wg = 8 XCDs x 96 (bijective).
  const int wgid = ((int)blockIdx.x & 7) * 96 + ((int)blockIdx.x >> 3);
  const int bx = wgid % 24, by = wgid / 24;
  const int m0 = by * 256, n0 = bx * 128;
  const int wr = wid >> 1, wc = wid & 1;

  auto stage = [&](int t, int buf) {
    const int k0 = t * 64;
    const int r8 = lane >> 3;
    const int blk = (lane & 7) ^ r8;
#pragma unroll
    for (int hh = 0; hh < 2; ++hh)
#pragma unroll
      for (int r = 0; r < 2; ++r) {
        int row = r * 64 + wid * 8 + r8;
        gload_lds16(A + (size_t)(m0 + hh * 128 + row) * K + k0 + blk * 8,
                    &As[buf][hh][r * 4096 + wid * 512]);
      }
#pragma unroll
    for (int r = 0; r < 2; ++r) {
      int row = r * 64 + wid * 8 + r8;
      gload_lds16(B + (size_t)(n0 + row) * K + k0 + blk * 8,
                  &Bs[buf][r * 4096 + wid * 512]);
    }
  };

  f32x16 acc[2][2] = {};

  stage(0, 0);
  asm volatile("s_waitcnt vmcnt(0)" ::: "memory");
  __builtin_amdgcn_sched_barrier(0);
  __builtin_amdgcn_s_barrier();
  __builtin_amdgcn_sched_barrier(0);

  int cur = 0;
  for (int t = 0; t < 16; ++t) {
    if (t + 1 < 16) stage(t + 1, cur ^ 1);  // issue early; land under compute

    bf16x8 af[2][4], bfr[2][4];
#pragma unroll
    for (int mi = 0; mi < 2; ++mi) {
      int row = (wr & 1) * 64 + mi * 32 + l31;
#pragma unroll
      for (int ks = 0; ks < 4; ++ks) {
        int chunk = (ks * 2 + h) ^ (row & 7);
        af[mi][ks] = *(const bf16x8*)&As[cur][wr >> 1][row * 64 + chunk * 8];
      }
    }
#pragma unroll
    for (int ni = 0; ni < 2; ++ni) {
      int row = wc * 64 + ni * 32 + l31;
#pragma unroll
      for (int ks = 0; ks < 4; ++ks) {
        int chunk = (ks * 2 + h) ^ (row & 7);
        bfr[ni][ks] = *(const bf16x8*)&Bs[cur][row * 64 + chunk * 8];
      }
    }
    __builtin_amdgcn_s_setprio(1);
#pragma unroll
    for (int ks = 0; ks < 4; ++ks)
#pragma unroll
      for (int mi = 0; mi < 2; ++mi)
#pragma unroll
        for (int ni = 0; ni < 2; ++ni)
          acc[mi][ni] = __builtin_amdgcn_mfma_f32_32x32x16_bf16(
              af[mi][ks], bfr[ni][ks], acc[mi][ni], 0, 0, 0);
    __builtin_amdgcn_s_setprio(0);

    asm volatile("s_waitcnt vmcnt(0)" ::: "memory");  // t+1 stages landed
    __builtin_amdgcn_sched_barrier(0);
    __builtin_amdgcn_s_barrier();
    __builtin_amdgcn_sched_barrier(0);
    cur ^= 1;
  }

  // epilogue: row = (reg&3)+8*(reg>>2)+4*h, col = l31 per 32x32 tile
#pragma unroll
  for (int mi = 0; mi < 2; ++mi)
#pragma unroll
    for (int ni = 0; ni < 2; ++ni)
#pragma unroll
      for (int reg = 0; reg < 16; ++reg) {
        int row = m0 + wr * 64 + mi * 32 + (reg & 3) + 8 * (reg >> 2) + 4 * h;
        int col = n0 + wc * 64 + ni * 32 + l31;
        C[(size_t)row * N + col] = f2b_rne(acc[mi][ni][reg]);
      }
}

// ---------------------------------------------------------------------------
// NT GEMM (proj): C[M,N] = A[M,K] * B[N,K]^T, bf16 in, fp32 out.
// ---------------------------------------------------------------------------
__global__ __launch_bounds__(256)
void gemm_nt(const unsigned short* __restrict__ A,
             const unsigned short* __restrict__ B,
             float* __restrict__ Cout, int M, int N, int K) {
  __shared__ __align__(16) unsigned short As[128][32];
  __shared__ __align__(16) unsigned short Bs[128][32];
  const int tid = threadIdx.x;
  const int w = tid >> 6, lane = tid & 63;
  const int l16 = lane & 15, lg = lane >> 4;
  const int wrow = (w >> 1) * 64, wcol = (w & 1) * 64;
  const int m0 = blockIdx.y * 128, n0 = blockIdx.x * 128;

  f32x4 acc[4][4] = {};

  auto stage = [&](int k0) {
#pragma unroll
    for (int c2 = 0; c2 < 2; ++c2) {
      int c = 2 * w + c2;
      const unsigned short* ga =
          A + (size_t)(m0 + 16 * c + (lane >> 2)) * K + k0 + (lane & 3) * 8;
      gload_lds16(ga, &As[16 * c][0]);
      const unsigned short* gb =
          B + (size_t)(n0 + 16 * c + (lane >> 2)) * K + k0 + (lane & 3) * 8;
      gload_lds16(gb, &Bs[16 * c][0]);
    }
  };

  stage(0);
  __syncthreads();
  const int nk = K >> 5;
  for (int ks = 0; ks < nk; ++ks) {
    bf16x8 af[4], bfr[4];
#pragma unroll
    for (int mi = 0; mi < 4; ++mi)
      af[mi] = *(const bf16x8*)&As[wrow + mi * 16 + l16][lg * 8];
#pragma unroll
    for (int ni = 0; ni < 4; ++ni)
      bfr[ni] = *(const bf16x8*)&Bs[wcol + ni * 16 + l16][lg * 8];
    __syncthreads();
    if (ks + 1 < nk) stage((ks + 1) * 32);
#pragma unroll
    for (int mi = 0; mi < 4; ++mi)
#pragma unroll
      for (int ni = 0; ni < 4; ++ni)
        acc[mi][ni] = __builtin_amdgcn_mfma_f32_16x16x32_bf16(
            af[mi], bfr[ni], acc[mi][ni], 0, 0, 0);
    __syncthreads();
  }

#pragma unroll
  for (int mi = 0; mi < 4; ++mi)
#pragma unroll
    for (int ni = 0; ni < 4; ++ni)
#pragma unroll
      for (int j = 0; j < 4; ++j) {
        int row = m0 + wrow + mi * 16 + lg * 4 + j;
        int col = n0 + wcol + ni * 16 + l16;
        Cout[(size_t)row * N + col] = acc[mi][ni][j];
      }
}

// ---------------------------------------------------------------------------
// Flash attention fwd, causal; swapped-QK^T 32x32 structure. (unchanged R9)
// ---------------------------------------------------------------------------
__global__ __launch_bounds__(256)
void attn_fwd(const unsigned short* __restrict__ qkv,
              const unsigned short* __restrict__ vt,
              unsigned short* __restrict__ out) {
  const int T = 2048, C3 = 3072;
  __shared__ __align__(16) unsigned short Ks[2][64][64];  // [kv][d] swizzled
  __shared__ __align__(16) unsigned short Vs[2][64][64];  // [d][kv] swizzled
  __shared__ float Bc[4][32];                             // per-wave broadcast

  const int tid = threadIdx.x, w = tid >> 6, lane = tid & 63;
  const int l31 = lane & 31, h = lane >> 5;
  const int wgid = (blockIdx.x & 7) * 128 + (blockIdx.x >> 3);
  const int qt = 15 - (wgid & 15);
  const int bh = wgid >> 4;
  const int b = bh >> 4, hed = bh & 15;
  const int qw = qt * 128 + w * 32;
  const size_t rowbase = (size_t)b * T * C3;
  const int hoff = hed * 64;
  const unsigned short* vbase = vt + (size_t)bh * 64 * 2048;
  const float c2 = 0.18033688f;  // 0.125 * log2(e)

  auto stageK = [&](int kv0, int buf) {
#pragma unroll
    for (int pp = 0; pp < 2; ++pp) {
      int chunk = w * 2 + pp;
      int row = chunk * 8 + (lane >> 3);
      int blk = (lane & 7) ^ (lane >> 3);
      gload_lds16(
          qkv + rowbase + (size_t)(kv0 + row) * C3 + 1024 + hoff + blk * 8,
          &Ks[buf][chunk * 8][0]);
    }
  };
  auto stageV = [&](int kv0, int buf) {
#pragma unroll
    for (int pp = 0; pp < 2; ++pp) {
      int chunk = w * 2 + pp;
      int drow = chunk * 8 + (lane >> 3);
      int blk = (lane & 7) ^ (lane >> 3);
      gload_lds16(vbase + (size_t)drow * 2048 + kv0 + blk * 8,
                  &Vs[buf][chunk * 8][0]);
    }
  };

  bf16x8 qf[4];
  {
    const unsigned short* qp =
        qkv + rowbase + (size_t)(qw + l31) * C3 + hoff + h * 8;
#pragma unroll
    for (int s = 0; s < 4; ++s) qf[s] = *(const bf16x8*)(qp + 16 * s);
  }

  f32x16 oacc[2] = {};
  float m_r = -1e30f, sum = 0.f;

  stageK(0, 0);
  stageV(0, 0);

  int cur = 0;
  const int ntiles = qt * 2 + 2;
  for (int t = 0; t < ntiles; ++t) {
    const int kv0 = t * 64;
    __builtin_amdgcn_s_barrier();
    if (t + 1 < ntiles) {
      stageK(kv0 + 64, cur ^ 1);
      stageV(kv0 + 64, cur ^ 1);
      asm volatile("s_waitcnt vmcnt(4)" ::: "memory");
    } else {
      asm volatile("s_waitcnt vmcnt(0)" ::: "memory");
    }
    __builtin_amdgcn_s_barrier();
    __builtin_amdgcn_sched_barrier(0);

    if (kv0 <= qw) {
      f32x16 sacc[2] = {};
      __builtin_amdgcn_s_setprio(1);
#pragma unroll
      for (int s = 0; s < 4; ++s) {
#pragma unroll
        for (int kt = 0; kt < 2; ++kt) {
          int row = kt * 32 + l31;
          int blk = (2 * s + h) ^ (row & 7);
          bf16x8 kf = *(const bf16x8*)&Ks[cur][row][blk * 8];
          sacc[kt] = __builtin_amdgcn_mfma_f32_32x32x16_bf16(kf, qf[s],
                                                             sacc[kt], 0, 0, 0);
        }
      }
      __builtin_amdgcn_s_setprio(0);
      if (kv0 + 64 > qw) {
        int q_abs = qw + l31;
#pragma unroll
        for (int kt = 0; kt < 2; ++kt)
#pragma unroll
          for (int r = 0; r < 16; ++r) {
            int kv_abs = kv0 + kt * 32 + (r & 3) + 8 * (r >> 2) + 4 * h;
            if (kv_abs > q_abs) sacc[kt][r] = -1e30f;
          }
      }
      float mx[8];
#pragma unroll
      for (int g = 0; g < 8; ++g)
        mx[g] = fmaxf(fmaxf(sacc[g >> 2][(g & 3) * 4 + 0],
                            sacc[g >> 2][(g & 3) * 4 + 1]),
                      fmaxf(sacc[g >> 2][(g & 3) * 4 + 2],
                            sacc[g >> 2][(g & 3) * 4 + 3]));
      float tm = fmaxf(fmaxf(fmaxf(mx[0], mx[1]), fmaxf(mx[2], mx[3])),
                       fmaxf(fmaxf(mx[4], mx[5]), fmaxf(mx[6], mx[7])));
      tm = fmaxf(tm, __shfl_xor(tm, 32));
      if (t == 0) {
        m_r = tm;
      } else if (!__all(tm <= m_r + 16.0f)) {
        float mnew = fmaxf(m_r, tm);
        float corr = __builtin_amdgcn_exp2f((m_r - mnew) * c2);
        sum *= corr;
        if (h == 0) Bc[w][l31] = corr;
        m_r = mnew;
        asm volatile("s_waitcnt lgkmcnt(0)" ::: "memory");
#pragma unroll
        for (int r = 0; r < 16; ++r) {
          float cr = Bc[w][(r & 3) + 8 * (r >> 2) + 4 * h];
          oacc[0][r] *= cr;
          oacc[1][r] *= cr;
        }
      }
      float m2 = m_r * c2;
      float s0 = 0.f, s1 = 0.f, s2 = 0.f, s3 = 0.f;
#pragma unroll
      for (int kt = 0; kt < 2; ++kt)
#pragma unroll
        for (int r = 0; r < 16; r += 4) {
          float p0 = __builtin_amdgcn_exp2f(fmaf(sacc[kt][r + 0], c2, -m2));
          float p1 = __builtin_amdgcn_exp2f(fmaf(sacc[kt][r + 1], c2, -m2));
          float p2 = __builtin_amdgcn_exp2f(fmaf(sacc[kt][r + 2], c2, -m2));
          float p3 = __builtin_amdgcn_exp2f(fmaf(sacc[kt][r + 3], c2, -m2));
          sacc[kt][r + 0] = p0; sacc[kt][r + 1] = p1;
          sacc[kt][r + 2] = p2; sacc[kt][r + 3] = p3;
          s0 += p0; s1 += p1; s2 += p2; s3 += p3;
        }
      float sl = (s0 + s1) + (s2 + s3);
      sum += sl + __shfl_xor(sl, 32);
      unsigned pk[16];
#pragma unroll
      for (int kt = 0; kt < 2; ++kt)
#pragma unroll
        for (int r = 0; r < 16; r += 2)
          pk[kt * 8 + (r >> 1)] = cvt_pk_bf16(sacc[kt][r], sacc[kt][r + 1]);
      __builtin_amdgcn_s_setprio(1);
#pragma unroll
      for (int sg = 0; sg < 4; ++sg) {
        const int kt = sg >> 1, s = sg & 1;
        const int base = kt * 8 + 4 * s;
        uint2v r02 = __builtin_amdgcn_permlane32_swap(pk[base], pk[base + 2],
                                                      false, false);
        uint2v r13 = __builtin_amdgcn_permlane32_swap(pk[base + 1], pk[base + 3],
                                                      false, false);
        union { unsigned u[4]; bf16x8 v; } Afr;
        Afr.u[0] = r02.x; Afr.u[1] = r13.x;
        Afr.u[2] = r02.y; Afr.u[3] = r13.y;
#pragma unroll
        for (int dt = 0; dt < 2; ++dt) {
          int d = dt * 32 + l31;
          int blk = (2 * sg + h) ^ (d & 7);
          bf16x8 vf = *(const bf16x8*)&Vs[cur][d][blk * 8];
          oacc[dt] = __builtin_amdgcn_mfma_f32_32x32x16_bf16(Afr.v, vf,
                                                             oacc[dt], 0, 0, 0);
        }
      }
      __builtin_amdgcn_s_setprio(0);
    }
    cur ^= 1;
  }

  if (h == 0) Bc[w][l31] = 1.0f / sum;
  asm volatile("s_waitcnt lgkmcnt(0)" ::: "memory");
#pragma unroll
  for (int r = 0; r < 16; ++r) {
    int ql = (r & 3) + 8 * (r >> 2) + 4 * h;
    float inv = Bc[w][ql];
    int q_abs = qw + ql;
#pragma unroll
    for (int dt = 0; dt < 2; ++dt) {
      out[(size_t)(b * T + q_abs) * 1024 + hoff + dt * 32 + l31] =
          f2b_rne(oacc[dt][r] * inv);
    }
  }
}

// ---------------------------------------------------------------------------
extern "C" void kernel_launch(void* const* d_in, const int* in_sizes, int n_in,
                              void* d_out, int out_size, void* d_ws,
                              size_t ws_size, hipStream_t stream) {
  const float* x = (const float*)d_in[0];      // [4,2048,1024]
  const float* w_qkv = (const float*)d_in[1];  // [3072,1024]
  const float* w_out = (const float*)d_in[2];  // [1024,1024]
  float* out = (float*)d_out;                  // [4,2048,1024] fp32

  const int M = 8192, C = 1024, C3 = 3072;

  unsigned short* xb = (unsigned short*)d_ws;      // M*C  (reused as attno)
  unsigned short* wqkvb = xb + (size_t)M * C;      // C3*C
  unsigned short* woutb = wqkvb + (size_t)C3 * C;  // C*C
  unsigned short* qkv = woutb + (size_t)C * C;     // M*C3
  unsigned short* vtb = qkv + (size_t)M * C3;      // B*H*64*T = M*C
  unsigned short* attno = xb;                      // alias: xb dead post-GEMM1

  f32_to_bf16_vec<<<1024, 256, 0, stream>>>(x, xb, M * C / 4);
  f32_to_bf16_vec<<<512, 256, 0, stream>>>(w_qkv, wqkvb, C3 * C / 4);
  f32_to_bf16_vec<<<256, 256, 0, stream>>>(w_out, woutb, C * C / 4);

  gemm_qkv<<<768, 512, 0, stream>>>(xb, wqkvb, qkv);

  v_transpose<<<dim3(32, 64), 256, 0, stream>>>(qkv, vtb);

  attn_fwd<<<1024, 256, 0, stream>>>(qkv, vtb, attno);

  gemm_nt<<<dim3(C / 128, M / 128), 256, 0, stream>>>(attno, woutb, out,
                                                      M, C, C);
}

// Round 11
// 192.155 us; speedup vs baseline: 1.2517x; 1.0588x over previous
//
#include <hip/hip_runtime.h>
#include <hip/hip_bf16.h>

// ---------------------------------------------------------------------------
// Fused causal MHA forward: x[B,T,C] fp32, w_qkv[3C,C] fp32, w_out[C,C] fp32
// B=4 T=2048 C=1024 H=16 hd=64.  All matmuls in bf16 MFMA, fp32 accumulate.
// convert->bf16 | GEMM qkv (256x128 mfma32) | V-transpose | flash-attn | proj.
// ---------------------------------------------------------------------------

typedef __attribute__((ext_vector_type(8))) short bf16x8;
typedef __attribute__((ext_vector_type(4))) float f32x4;
typedef __attribute__((ext_vector_type(16))) float f32x16;
typedef __attribute__((ext_vector_type(2))) unsigned uint2v;

#define GLOBAL_AS __attribute__((address_space(1)))
#define LDS_AS __attribute__((address_space(3)))

__device__ __forceinline__ unsigned short f2b_rne(float f) {
  unsigned u = __float_as_uint(f);
  unsigned r = u + 0x7fffu + ((u >> 16) & 1u);
  return (unsigned short)(r >> 16);
}

__device__ __forceinline__ unsigned cvt_pk_bf16(float lo, float hi) {
  unsigned r;
  asm("v_cvt_pk_bf16_f32 %0, %1, %2" : "=v"(r) : "v"(lo), "v"(hi));
  return r;
}

__device__ __forceinline__ void gload_lds16(const void* g, void* l) {
  __builtin_amdgcn_global_load_lds((const GLOBAL_AS void*)g, (LDS_AS void*)l, 16, 0, 0);
}

// ---------------------------------------------------------------------------
// fp32 -> bf16 conversion (vectorized, grid-stride)
// ---------------------------------------------------------------------------
__global__ void f32_to_bf16_vec(const float* __restrict__ src,
                                unsigned short* __restrict__ dst, int n4) {
  int i = blockIdx.x * blockDim.x + threadIdx.x;
  int stride = gridDim.x * blockDim.x;
  for (; i < n4; i += stride) {
    float4 v = reinterpret_cast<const float4*>(src)[i];
    ushort4 o;
    o.x = f2b_rne(v.x); o.y = f2b_rne(v.y);
    o.z = f2b_rne(v.z); o.w = f2b_rne(v.w);
    reinterpret_cast<ushort4*>(dst)[i] = o;
  }
}

// ---------------------------------------------------------------------------
// V transpose: qkv V-block rows -> vt[bh][d][T] via swizzled 64x64 LDS tile.
// ---------------------------------------------------------------------------
__global__ __launch_bounds__(256)
void v_transpose(const unsigned short* __restrict__ qkv,
                 unsigned short* __restrict__ vt) {
  __shared__ __align__(16) unsigned short Ts[64][64];
  const int tc = blockIdx.x, bh = blockIdx.y;
  const int b = bh >> 4, hed = bh & 15;
  const int t0 = tc * 64;
  const int tid = threadIdx.x;
  {
    const int r = tid >> 2, cb = (tid & 3) * 2;
    const unsigned short* src =
        qkv + (size_t)(b * 2048 + t0 + r) * 3072 + 2048 + hed * 64;
    bf16x8 v0 = *(const bf16x8*)(src + cb * 8);
    bf16x8 v1 = *(const bf16x8*)(src + cb * 8 + 8);
    *(bf16x8*)&Ts[r][(cb ^ (r & 7)) * 8] = v0;
    *(bf16x8*)&Ts[r][((cb + 1) ^ (r & 7)) * 8] = v1;
  }
  __syncthreads();
  const int d = tid >> 2;
  unsigned short* dst = vt + ((size_t)bh * 64 + d) * 2048 + t0;
#pragma unroll
  for (int tb2 = 0; tb2 < 2; ++tb2) {
    int tb = (tid & 3) * 2 + tb2;
    union { unsigned short s[8]; bf16x8 v; } o;
#pragma unroll
    for (int i = 0; i < 8; ++i) {
      int row = tb * 8 + i;
      o.s[i] = Ts[row][(((d >> 3) ^ (row & 7)) * 8) + (d & 7)];
    }
    *(bf16x8*)(dst + tb * 8) = o.v;
  }
}

// ---------------------------------------------------------------------------
// QKV GEMM: 256x128 tile, 8 waves, BK=64, mfma_32x32x16. (unchanged R10)
// ---------------------------------------------------------------------------
__global__ __launch_bounds__(512, 2)
void gemm_qkv(const unsigned short* __restrict__ A,
              const unsigned short* __restrict__ B,
              unsigned short* __restrict__ C) {
  const int K = 1024, N = 3072;
  __shared__ __align__(16) unsigned short As[2][2][128 * 64];
  __shared__ __align__(16) unsigned short Bs[2][128 * 64];

  const int tid = threadIdx.x, wid = tid >> 6, lane = tid & 63;
  const int l31 = lane & 31, h = lane >> 5;
  const int wgid = ((int)blockIdx.x & 7) * 96 + ((int)blockIdx.x >> 3);
  const int bx = wgid % 24, by = wgid / 24;
  const int m0 = by * 256, n0 = bx * 128;
  const int wr = wid >> 1, wc = wid & 1;

  auto stage = [&](int t, int buf) {
    const int k0 = t * 64;
    const int r8 = lane >> 3;
    const int blk = (lane & 7) ^ r8;
#pragma unroll
    for (int hh = 0; hh < 2; ++hh)
#pragma unroll
      for (int r = 0; r < 2; ++r) {
        int row = r * 64 + wid * 8 + r8;
        gload_lds16(A + (size_t)(m0 + hh * 128 + row) * K + k0 + blk * 8,
                    &As[buf][hh][r * 4096 + wid * 512]);
      }
#pragma unroll
    for (int r = 0; r < 2; ++r) {
      int row = r * 64 + wid * 8 + r8;
      gload_lds16(B + (size_t)(n0 + row) * K + k0 + blk * 8,
                  &Bs[buf][r * 4096 + wid * 512]);
    }
  };

  f32x16 acc[2][2] = {};

  stage(0, 0);
  asm volatile("s_waitcnt vmcnt(0)" ::: "memory");
  __builtin_amdgcn_sched_barrier(0);
  __builtin_amdgcn_s_barrier();
  __builtin_amdgcn_sched_barrier(0);

  int cur = 0;
  for (int t = 0; t < 16; ++t) {
    if (t + 1 < 16) stage(t + 1, cur ^ 1);

    bf16x8 af[2][4], bfr[2][4];
#pragma unroll
    for (int mi = 0; mi < 2; ++mi) {
      int row = (wr & 1) * 64 + mi * 32 + l31;
#pragma unroll
      for (int ks = 0; ks < 4; ++ks) {
        int chunk = (ks * 2 + h) ^ (row & 7);
        af[mi][ks] = *(const bf16x8*)&As[cur][wr >> 1][row * 64 + chunk * 8];
      }
    }
#pragma unroll
    for (int ni = 0; ni < 2; ++ni) {
      int row = wc * 64 + ni * 32 + l31;
#pragma unroll
      for (int ks = 0; ks < 4; ++ks) {
        int chunk = (ks * 2 + h) ^ (row & 7);
        bfr[ni][ks] = *(const bf16x8*)&Bs[cur][row * 64 + chunk * 8];
      }
    }
    __builtin_amdgcn_s_setprio(1);
#pragma unroll
    for (int ks = 0; ks < 4; ++ks)
#pragma unroll
      for (int mi = 0; mi < 2; ++mi)
#pragma unroll
        for (int ni = 0; ni < 2; ++ni)
          acc[mi][ni] = __builtin_amdgcn_mfma_f32_32x32x16_bf16(
              af[mi][ks], bfr[ni][ks], acc[mi][ni], 0, 0, 0);
    __builtin_amdgcn_s_setprio(0);

    asm volatile("s_waitcnt vmcnt(0)" ::: "memory");
    __builtin_amdgcn_sched_barrier(0);
    __builtin_amdgcn_s_barrier();
    __builtin_amdgcn_sched_barrier(0);
    cur ^= 1;
  }

#pragma unroll
  for (int mi = 0; mi < 2; ++mi)
#pragma unroll
    for (int ni = 0; ni < 2; ++ni)
#pragma unroll
      for (int reg = 0; reg < 16; ++reg) {
        int row = m0 + wr * 64 + mi * 32 + (reg & 3) + 8 * (reg >> 2) + 4 * h;
        int col = n0 + wc * 64 + ni * 32 + l31;
        C[(size_t)row * N + col] = f2b_rne(acc[mi][ni][reg]);
      }
}

// ---------------------------------------------------------------------------
// NT GEMM (proj): C[M,N] = A[M,K] * B[N,K]^T, bf16 in, fp32 out. (unchanged)
// ---------------------------------------------------------------------------
__global__ __launch_bounds__(256)
void gemm_nt(const unsigned short* __restrict__ A,
             const unsigned short* __restrict__ B,
             float* __restrict__ Cout, int M, int N, int K) {
  __shared__ __align__(16) unsigned short As[128][32];
  __shared__ __align__(16) unsigned short Bs[128][32];
  const int tid = threadIdx.x;
  const int w = tid >> 6, lane = tid & 63;
  const int l16 = lane & 15, lg = lane >> 4;
  const int wrow = (w >> 1) * 64, wcol = (w & 1) * 64;
  const int m0 = blockIdx.y * 128, n0 = blockIdx.x * 128;

  f32x4 acc[4][4] = {};

  auto stage = [&](int k0) {
#pragma unroll
    for (int c2 = 0; c2 < 2; ++c2) {
      int c = 2 * w + c2;
      const unsigned short* ga =
          A + (size_t)(m0 + 16 * c + (lane >> 2)) * K + k0 + (lane & 3) * 8;
      gload_lds16(ga, &As[16 * c][0]);
      const unsigned short* gb =
          B + (size_t)(n0 + 16 * c + (lane >> 2)) * K + k0 + (lane & 3) * 8;
      gload_lds16(gb, &Bs[16 * c][0]);
    }
  };

  stage(0);
  __syncthreads();
  const int nk = K >> 5;
  for (int ks = 0; ks < nk; ++ks) {
    bf16x8 af[4], bfr[4];
#pragma unroll
    for (int mi = 0; mi < 4; ++mi)
      af[mi] = *(const bf16x8*)&As[wrow + mi * 16 + l16][lg * 8];
#pragma unroll
    for (int ni = 0; ni < 4; ++ni)
      bfr[ni] = *(const bf16x8*)&Bs[wcol + ni * 16 + l16][lg * 8];
    __syncthreads();
    if (ks + 1 < nk) stage((ks + 1) * 32);
#pragma unroll
    for (int mi = 0; mi < 4; ++mi)
#pragma unroll
      for (int ni = 0; ni < 4; ++ni)
        acc[mi][ni] = __builtin_amdgcn_mfma_f32_16x16x32_bf16(
            af[mi], bfr[ni], acc[mi][ni], 0, 0, 0);
    __syncthreads();
  }

#pragma unroll
  for (int mi = 0; mi < 4; ++mi)
#pragma unroll
    for (int ni = 0; ni < 4; ++ni)
#pragma unroll
      for (int j = 0; j < 4; ++j) {
        int row = m0 + wrow + mi * 16 + lg * 4 + j;
        int col = n0 + wcol + ni * 16 + l16;
        Cout[(size_t)row * N + col] = acc[mi][ni][j];
      }
}

// ---------------------------------------------------------------------------
// Flash attention fwd, causal; swapped-QK^T 32x32; 64 q-rows per wave
// (two 32-row halves sharing each staged K tile: K-frag read once -> 2 MFMAs).
// Block: 4 waves x 64 q = 256 q-rows; qt in 0..7; KV tile 64 double-buffered.
// Counted-vmcnt pipeline (R9).  Complementary qt pairing across the XCD so
// RR CU assignment gets constant total work (36 iterations per CU).
// ---------------------------------------------------------------------------
__global__ __launch_bounds__(256, 2)
void attn_fwd(const unsigned short* __restrict__ qkv,
              const unsigned short* __restrict__ vt,
              unsigned short* __restrict__ out) {
  const int T = 2048, C3 = 3072;
  __shared__ __align__(16) unsigned short Ks[2][64][64];  // [kv][d] swizzled
  __shared__ __align__(16) unsigned short Vs[2][64][64];  // [d][kv] swizzled
  __shared__ float Bc[4][32];                             // per-wave broadcast

  const int tid = threadIdx.x, w = tid >> 6, lane = tid & 63;
  const int l31 = lane & 31, h = lane >> 5;
  // 512 blocks = 8 XCDs x 64.  local = qidx*8 + bh_l; complementary qt map.
  const int wgid = (blockIdx.x & 7) * 64 + (blockIdx.x >> 3);
  const int local = wgid & 63, xcd = wgid >> 6;
  const int qidx = local >> 3, bhl = local & 7;
  const int bh = xcd * 8 + bhl;
  const int qt = (qidx < 4) ? (7 - qidx) : (qidx - 4);
  const int b = bh >> 4, hed = bh & 15;
  const int qw = qt * 256 + w * 64;  // wave covers rows qw .. qw+63
  const size_t rowbase = (size_t)b * T * C3;
  const int hoff = hed * 64;
  const unsigned short* vbase = vt + (size_t)bh * 64 * 2048;
  const float c2 = 0.18033688f;  // 0.125 * log2(e)

  auto stageK = [&](int kv0, int buf) {
#pragma unroll
    for (int pp = 0; pp < 2; ++pp) {
      int chunk = w * 2 + pp;
      int row = chunk * 8 + (lane >> 3);
      int blk = (lane & 7) ^ (lane >> 3);
      gload_lds16(
          qkv + rowbase + (size_t)(kv0 + row) * C3 + 1024 + hoff + blk * 8,
          &Ks[buf][chunk * 8][0]);
    }
  };
  auto stageV = [&](int kv0, int buf) {
#pragma unroll
    for (int pp = 0; pp < 2; ++pp) {
      int chunk = w * 2 + pp;
      int drow = chunk * 8 + (lane >> 3);
      int blk = (lane & 7) ^ (lane >> 3);
      gload_lds16(vbase + (size_t)drow * 2048 + kv0 + blk * 8,
                  &Vs[buf][chunk * 8][0]);
    }
  };

  // Q frags per half X: qf[X][s] = Q[qw+32X+l31][hoff + 16s + 8h ..+8)
  bf16x8 qf0[4], qf1[4];
  {
    const unsigned short* qp0 =
        qkv + rowbase + (size_t)(qw + l31) * C3 + hoff + h * 8;
    const unsigned short* qp1 = qp0 + 32 * C3;
#pragma unroll
    for (int s = 0; s < 4; ++s) {
      qf0[s] = *(const bf16x8*)(qp0 + 16 * s);
      qf1[s] = *(const bf16x8*)(qp1 + 16 * s);
    }
  }

  f32x16 oacc0[2] = {}, oacc1[2] = {};
  float mr0 = -1e30f, mr1 = -1e30f, sum0 = 0.f, sum1 = 0.f;

  stageK(0, 0);
  stageV(0, 0);

  // softmax + PV for one 32-row half (sacc consumed; V-frags read per half)
  auto do_half = [&](f32x16 (&sacc)[2], int qx, float& mr, float& sm,
                     f32x16 (&oc)[2], int t, int kv0, int cur) {
    if (kv0 + 64 > qx) {  // diagonal tile
      int q_abs = qx + l31;
#pragma unroll
      for (int kt = 0; kt < 2; ++kt)
#pragma unroll
        for (int r = 0; r < 16; ++r) {
          int kv_abs = kv0 + kt * 32 + (r & 3) + 8 * (r >> 2) + 4 * h;
          if (kv_abs > q_abs) sacc[kt][r] = -1e30f;
        }
    }
    float mx[8];
#pragma unroll
    for (int g = 0; g < 8; ++g)
      mx[g] = fmaxf(fmaxf(sacc[g >> 2][(g & 3) * 4 + 0],
                          sacc[g >> 2][(g & 3) * 4 + 1]),
                    fmaxf(sacc[g >> 2][(g & 3) * 4 + 2],
                          sacc[g >> 2][(g & 3) * 4 + 3]));
    float tm = fmaxf(fmaxf(fmaxf(mx[0], mx[1]), fmaxf(mx[2], mx[3])),
                     fmaxf(fmaxf(mx[4], mx[5]), fmaxf(mx[6], mx[7])));
    tm = fmaxf(tm, __shfl_xor(tm, 32));
    if (t == 0) {
      mr = tm;
    } else if (!__all(tm <= mr + 16.0f)) {
      float mnew = fmaxf(mr, tm);
      float corr = __builtin_amdgcn_exp2f((mr - mnew) * c2);
      sm *= corr;
      if (h == 0) Bc[w][l31] = corr;
      mr = mnew;
      asm volatile("s_waitcnt lgkmcnt(0)" ::: "memory");
#pragma unroll
      for (int r = 0; r < 16; ++r) {
        float cr = Bc[w][(r & 3) + 8 * (r >> 2) + 4 * h];
        oc[0][r] *= cr;
        oc[1][r] *= cr;
      }
    }
    float m2 = mr * c2;
    float s0 = 0.f, s1 = 0.f, s2 = 0.f, s3 = 0.f;
#pragma unroll
    for (int kt = 0; kt < 2; ++kt)
#pragma unroll
      for (int r = 0; r < 16; r += 4) {
        float p0 = __builtin_amdgcn_exp2f(fmaf(sacc[kt][r + 0], c2, -m2));
        float p1 = __builtin_amdgcn_exp2f(fmaf(sacc[kt][r + 1], c2, -m2));
        float p2 = __builtin_amdgcn_exp2f(fmaf(sacc[kt][r + 2], c2, -m2));
        float p3 = __builtin_amdgcn_exp2f(fmaf(sacc[kt][r + 3], c2, -m2));
        sacc[kt][r + 0] = p0; sacc[kt][r + 1] = p1;
        sacc[kt][r + 2] = p2; sacc[kt][r + 3] = p3;
        s0 += p0; s1 += p1; s2 += p2; s3 += p3;
      }
    float sl = (s0 + s1) + (s2 + s3);
    sm += sl + __shfl_xor(sl, 32);
    unsigned pk[16];
#pragma unroll
    for (int kt = 0; kt < 2; ++kt)
#pragma unroll
      for (int r = 0; r < 16; r += 2)
        pk[kt * 8 + (r >> 1)] = cvt_pk_bf16(sacc[kt][r], sacc[kt][r + 1]);
    __builtin_amdgcn_s_setprio(1);
#pragma unroll
    for (int sg = 0; sg < 4; ++sg) {
      const int kt = sg >> 1, s = sg & 1;
      const int base = kt * 8 + 4 * s;
      uint2v r02 = __builtin_amdgcn_permlane32_swap(pk[base], pk[base + 2],
                                                    false, false);
      uint2v r13 = __builtin_amdgcn_permlane32_swap(pk[base + 1], pk[base + 3],
                                                    false, false);
      union { unsigned u[4]; bf16x8 v; } Afr;
      Afr.u[0] = r02.x; Afr.u[1] = r13.x;
      Afr.u[2] = r02.y; Afr.u[3] = r13.y;
#pragma unroll
      for (int dt = 0; dt < 2; ++dt) {
        int d = dt * 32 + l31;
        int blk = (2 * sg + h) ^ (d & 7);
        bf16x8 vf = *(const bf16x8*)&Vs[cur][d][blk * 8];
        oc[dt] = __builtin_amdgcn_mfma_f32_32x32x16_bf16(Afr.v, vf,
                                                         oc[dt], 0, 0, 0);
      }
    }
    __builtin_amdgcn_s_setprio(0);
  };

  int cur = 0;
  const int ntiles = 4 * qt + 4;
  for (int t = 0; t < ntiles; ++t) {
    const int kv0 = t * 64;
    __builtin_amdgcn_s_barrier();
    if (t + 1 < ntiles) {
      stageK(kv0 + 64, cur ^ 1);
      stageV(kv0 + 64, cur ^ 1);
      asm volatile("s_waitcnt vmcnt(4)" ::: "memory");
    } else {
      asm volatile("s_waitcnt vmcnt(0)" ::: "memory");
    }
    __builtin_amdgcn_s_barrier();
    __builtin_amdgcn_sched_barrier(0);

    if (kv0 <= qw) {  // wave participates (rows qw..qw+63)
      // ---- S^T for both halves; each K-frag read once, used twice ----
      f32x16 sacc0[2] = {}, sacc1[2] = {};
      __builtin_amdgcn_s_setprio(1);
#pragma unroll
      for (int s = 0; s < 4; ++s) {
#pragma unroll
        for (int kt = 0; kt < 2; ++kt) {
          int row = kt * 32 + l31;
          int blk = (2 * s + h) ^ (row & 7);
          bf16x8 kf = *(const bf16x8*)&Ks[cur][row][blk * 8];
          sacc0[kt] = __builtin_amdgcn_mfma_f32_32x32x16_bf16(kf, qf0[s],
                                                              sacc0[kt], 0, 0, 0);
          sacc1[kt] = __builtin_amdgcn_mfma_f32_32x32x16_bf16(kf, qf1[s],
                                                              sacc1[kt], 0, 0, 0);
        }
      }
      __builtin_amdgcn_s_setprio(0);
      do_half(sacc0, qw, mr0, sum0, oacc0, t, kv0, cur);
      do_half(sacc1, qw + 32, mr1, sum1, oacc1, t, kv0, cur);
    }
    cur ^= 1;
  }

  // ---- epilogue: both halves ----
#pragma unroll
  for (int X = 0; X < 2; ++X) {
    float sm = X ? sum1 : sum0;
    if (h == 0) Bc[w][l31] = 1.0f / sm;
    asm volatile("s_waitcnt lgkmcnt(0)" ::: "memory");
#pragma unroll
    for (int r = 0; r < 16; ++r) {
      int ql = (r & 3) + 8 * (r >> 2) + 4 * h;
      float inv = Bc[w][ql];
      int q_abs = qw + 32 * X + ql;
#pragma unroll
      for (int dt = 0; dt < 2; ++dt) {
        float v = (X ? oacc1 : oacc0)[dt][r] * inv;
        out[(size_t)(b * T + q_abs) * 1024 + hoff + dt * 32 + l31] =
            f2b_rne(v);
      }
    }
    __builtin_amdgcn_s_barrier();  // Bc reuse between halves (cross-wave safe)
  }
}

// ---------------------------------------------------------------------------
extern "C" void kernel_launch(void* const* d_in, const int* in_sizes, int n_in,
                              void* d_out, int out_size, void* d_ws,
                              size_t ws_size, hipStream_t stream) {
  const float* x = (const float*)d_in[0];      // [4,2048,1024]
  const float* w_qkv = (const float*)d_in[1];  // [3072,1024]
  const float* w_out = (const float*)d_in[2];  // [1024,1024]
  float* out = (float*)d_out;                  // [4,2048,1024] fp32

  const int M = 8192, C = 1024, C3 = 3072;

  unsigned short* xb = (unsigned short*)d_ws;      // M*C  (reused as attno)
  unsigned short* wqkvb = xb + (size_t)M * C;      // C3*C
  unsigned short* woutb = wqkvb + (size_t)C3 * C;  // C*C
  unsigned short* qkv = woutb + (size_t)C * C;     // M*C3
  unsigned short* vtb = qkv + (size_t)M * C3;      // B*H*64*T = M*C
  unsigned short* attno = xb;                      // alias: xb dead post-GEMM1

  f32_to_bf16_vec<<<1024, 256, 0, stream>>>(x, xb, M * C / 4);
  f32_to_bf16_vec<<<512, 256, 0, stream>>>(w_qkv, wqkvb, C3 * C / 4);
  f32_to_bf16_vec<<<256, 256, 0, stream>>>(w_out, woutb, C * C / 4);

  gemm_qkv<<<768, 512, 0, stream>>>(xb, wqkvb, qkv);

  v_transpose<<<dim3(32, 64), 256, 0, stream>>>(qkv, vtb);

  attn_fwd<<<512, 256, 0, stream>>>(qkv, vtb, attno);

  gemm_nt<<<dim3(C / 128, M / 128), 256, 0, stream>>>(attno, woutb, out,
                                                      M, C, C);
}

// Round 12
// 189.785 us; speedup vs baseline: 1.2673x; 1.0125x over previous
//
#include <hip/hip_runtime.h>
#include <hip/hip_bf16.h>

// ---------------------------------------------------------------------------
// Fused causal MHA forward: x[B,T,C] fp32, w_qkv[3C,C] fp32, w_out[C,C] fp32
// B=4 T=2048 C=1024 H=16 hd=64.  All matmuls in bf16 MFMA, fp32 accumulate.
// convert->bf16 | GEMM qkv | V-transpose | flash-attn | GEMM proj.
// Both GEMMs: 256x128 tile, 8 waves, BK=64, mfma_32x32x16, counted-vmcnt.
// ---------------------------------------------------------------------------

typedef __attribute__((ext_vector_type(8))) short bf16x8;
typedef __attribute__((ext_vector_type(4))) float f32x4;
typedef __attribute__((ext_vector_type(16))) float f32x16;
typedef __attribute__((ext_vector_type(2))) unsigned uint2v;

#define GLOBAL_AS __attribute__((address_space(1)))
#define LDS_AS __attribute__((address_space(3)))

__device__ __forceinline__ unsigned short f2b_rne(float f) {
  unsigned u = __float_as_uint(f);
  unsigned r = u + 0x7fffu + ((u >> 16) & 1u);
  return (unsigned short)(r >> 16);
}

__device__ __forceinline__ unsigned cvt_pk_bf16(float lo, float hi) {
  unsigned r;
  asm("v_cvt_pk_bf16_f32 %0, %1, %2" : "=v"(r) : "v"(lo), "v"(hi));
  return r;
}

__device__ __forceinline__ void gload_lds16(const void* g, void* l) {
  __builtin_amdgcn_global_load_lds((const GLOBAL_AS void*)g, (LDS_AS void*)l, 16, 0, 0);
}

// ---------------------------------------------------------------------------
// fp32 -> bf16 conversion (vectorized, grid-stride)
// ---------------------------------------------------------------------------
__global__ void f32_to_bf16_vec(const float* __restrict__ src,
                                unsigned short* __restrict__ dst, int n4) {
  int i = blockIdx.x * blockDim.x + threadIdx.x;
  int stride = gridDim.x * blockDim.x;
  for (; i < n4; i += stride) {
    float4 v = reinterpret_cast<const float4*>(src)[i];
    ushort4 o;
    o.x = f2b_rne(v.x); o.y = f2b_rne(v.y);
    o.z = f2b_rne(v.z); o.w = f2b_rne(v.w);
    reinterpret_cast<ushort4*>(dst)[i] = o;
  }
}

// ---------------------------------------------------------------------------
// V transpose: qkv V-block rows -> vt[bh][d][T] via swizzled 64x64 LDS tile.
// ---------------------------------------------------------------------------
__global__ __launch_bounds__(256)
void v_transpose(const unsigned short* __restrict__ qkv,
                 unsigned short* __restrict__ vt) {
  __shared__ __align__(16) unsigned short Ts[64][64];
  const int tc = blockIdx.x, bh = blockIdx.y;
  const int b = bh >> 4, hed = bh & 15;
  const int t0 = tc * 64;
  const int tid = threadIdx.x;
  {
    const int r = tid >> 2, cb = (tid & 3) * 2;
    const unsigned short* src =
        qkv + (size_t)(b * 2048 + t0 + r) * 3072 + 2048 + hed * 64;
    bf16x8 v0 = *(const bf16x8*)(src + cb * 8);
    bf16x8 v1 = *(const bf16x8*)(src + cb * 8 + 8);
    *(bf16x8*)&Ts[r][(cb ^ (r & 7)) * 8] = v0;
    *(bf16x8*)&Ts[r][((cb + 1) ^ (r & 7)) * 8] = v1;
  }
  __syncthreads();
  const int d = tid >> 2;
  unsigned short* dst = vt + ((size_t)bh * 64 + d) * 2048 + t0;
#pragma unroll
  for (int tb2 = 0; tb2 < 2; ++tb2) {
    int tb = (tid & 3) * 2 + tb2;
    union { unsigned short s[8]; bf16x8 v; } o;
#pragma unroll
    for (int i = 0; i < 8; ++i) {
      int row = tb * 8 + i;
      o.s[i] = Ts[row][(((d >> 3) ^ (row & 7)) * 8) + (d & 7)];
    }
    *(bf16x8*)(dst + tb * 8) = o.v;
  }
}

// ---------------------------------------------------------------------------
// Big GEMM template: C[M,N] = A[M,1024] * B[N,1024]^T.
// 256x128 tile, 8 waves (4Mx2N), BK=64, mfma_32x32x16.  Counted-vmcnt loop:
// barrier / stage(t+1)+vmcnt(6) (waits only loads issued one iter ago) /
// barrier / compute.  96 KB LDS -> 1 block/CU; pipeline depth replaces TLP.
// ---------------------------------------------------------------------------
template <int N, int OUT_BF16>
__global__ __launch_bounds__(512)
void gemm_big(const unsigned short* __restrict__ A,
              const unsigned short* __restrict__ B,
              void* __restrict__ Cout) {
  const int K = 1024;
  __shared__ __align__(16) unsigned short As[2][2][128 * 64];
  __shared__ __align__(16) unsigned short Bs[2][128 * 64];

  const int tid = threadIdx.x, wid = tid >> 6, lane = tid & 63;
  const int l31 = lane & 31, h = lane >> 5;
  const int NBX = N / 128;
  const int nwg8 = (int)gridDim.x >> 3;  // grid divisible by 8 -> bijective
  const int wgid = ((int)blockIdx.x & 7) * nwg8 + ((int)blockIdx.x >> 3);
  const int bx = wgid % NBX, by = wgid / NBX;
  const int m0 = by * 256, n0 = bx * 128;
  const int wr = wid >> 1, wc = wid & 1;

  auto stage = [&](int t, int buf) {
    const int k0 = t * 64;
    const int r8 = lane >> 3;
    const int blk = (lane & 7) ^ r8;
#pragma unroll
    for (int hh = 0; hh < 2; ++hh)
#pragma unroll
      for (int r = 0; r < 2; ++r) {
        int row = r * 64 + wid * 8 + r8;
        gload_lds16(A + (size_t)(m0 + hh * 128 + row) * K + k0 + blk * 8,
                    &As[buf][hh][r * 4096 + wid * 512]);
      }
#pragma unroll
    for (int r = 0; r < 2; ++r) {
      int row = r * 64 + wid * 8 + r8;
      gload_lds16(B + (size_t)(n0 + row) * K + k0 + blk * 8,
                  &Bs[buf][r * 4096 + wid * 512]);
    }
  };

  f32x16 acc[2][2] = {};

  stage(0, 0);

  int cur = 0;
  for (int t = 0; t < 16; ++t) {
    // barrier A: all waves done reading buf[cur^1] (iter t-1's fragments)
    __builtin_amdgcn_s_barrier();
    if (t + 1 < 16) {
      stage(t + 1, cur ^ 1);  // issue; stays in flight across the tile
      asm volatile("s_waitcnt vmcnt(6)" ::: "memory");  // waits stage(t) only
    } else {
      asm volatile("s_waitcnt vmcnt(0)" ::: "memory");
    }
    // barrier B: every wave's stage(t) landed in LDS
    __builtin_amdgcn_s_barrier();
    __builtin_amdgcn_sched_barrier(0);

    bf16x8 af[2][4], bfr[2][4];
#pragma unroll
    for (int mi = 0; mi < 2; ++mi) {
      int row = (wr & 1) * 64 + mi * 32 + l31;
#pragma unroll
      for (int ks = 0; ks < 4; ++ks) {
        int chunk = (ks * 2 + h) ^ (row & 7);
        af[mi][ks] = *(const bf16x8*)&As[cur][wr >> 1][row * 64 + chunk * 8];
      }
    }
#pragma unroll
    for (int ni = 0; ni < 2; ++ni) {
      int row = wc * 64 + ni * 32 + l31;
#pragma unroll
      for (int ks = 0; ks < 4; ++ks) {
        int chunk = (ks * 2 + h) ^ (row & 7);
        bfr[ni][ks] = *(const bf16x8*)&Bs[cur][row * 64 + chunk * 8];
      }
    }
    __builtin_amdgcn_s_setprio(1);
#pragma unroll
    for (int ks = 0; ks < 4; ++ks)
#pragma unroll
      for (int mi = 0; mi < 2; ++mi)
#pragma unroll
        for (int ni = 0; ni < 2; ++ni)
          acc[mi][ni] = __builtin_amdgcn_mfma_f32_32x32x16_bf16(
              af[mi][ks], bfr[ni][ks], acc[mi][ni], 0, 0, 0);
    __builtin_amdgcn_s_setprio(0);
    cur ^= 1;
  }

  // epilogue: row = (reg&3)+8*(reg>>2)+4*h, col = l31 per 32x32 tile
#pragma unroll
  for (int mi = 0; mi < 2; ++mi)
#pragma unroll
    for (int ni = 0; ni < 2; ++ni)
#pragma unroll
      for (int reg = 0; reg < 16; ++reg) {
        int row = m0 + wr * 64 + mi * 32 + (reg & 3) + 8 * (reg >> 2) + 4 * h;
        int col = n0 + wc * 64 + ni * 32 + l31;
        if (OUT_BF16)
          ((unsigned short*)Cout)[(size_t)row * N + col] =
              f2b_rne(acc[mi][ni][reg]);
        else
          ((float*)Cout)[(size_t)row * N + col] = acc[mi][ni][reg];
      }
}

// ---------------------------------------------------------------------------
// Flash attention fwd, causal; swapped-QK^T 32x32; 64 q-rows per wave.
// (unchanged from R11)
// ---------------------------------------------------------------------------
__global__ __launch_bounds__(256, 2)
void attn_fwd(const unsigned short* __restrict__ qkv,
              const unsigned short* __restrict__ vt,
              unsigned short* __restrict__ out) {
  const int T = 2048, C3 = 3072;
  __shared__ __align__(16) unsigned short Ks[2][64][64];  // [kv][d] swizzled
  __shared__ __align__(16) unsigned short Vs[2][64][64];  // [d][kv] swizzled
  __shared__ float Bc[4][32];                             // per-wave broadcast

  const int tid = threadIdx.x, w = tid >> 6, lane = tid & 63;
  const int l31 = lane & 31, h = lane >> 5;
  const int wgid = (blockIdx.x & 7) * 64 + (blockIdx.x >> 3);
  const int local = wgid & 63, xcd = wgid >> 6;
  const int qidx = local >> 3, bhl = local & 7;
  const int bh = xcd * 8 + bhl;
  const int qt = (qidx < 4) ? (7 - qidx) : (qidx - 4);
  const int b = bh >> 4, hed = bh & 15;
  const int qw = qt * 256 + w * 64;
  const size_t rowbase = (size_t)b * T * C3;
  const int hoff = hed * 64;
  const unsigned short* vbase = vt + (size_t)bh * 64 * 2048;
  const float c2 = 0.18033688f;  // 0.125 * log2(e)

  auto stageK = [&](int kv0, int buf) {
#pragma unroll
    for (int pp = 0; pp < 2; ++pp) {
      int chunk = w * 2 + pp;
      int row = chunk * 8 + (lane >> 3);
      int blk = (lane & 7) ^ (lane >> 3);
      gload_lds16(
          qkv + rowbase + (size_t)(kv0 + row) * C3 + 1024 + hoff + blk * 8,
          &Ks[buf][chunk * 8][0]);
    }
  };
  auto stageV = [&](int kv0, int buf) {
#pragma unroll
    for (int pp = 0; pp < 2; ++pp) {
      int chunk = w * 2 + pp;
      int drow = chunk * 8 + (lane >> 3);
      int blk = (lane & 7) ^ (lane >> 3);
      gload_lds16(vbase + (size_t)drow * 2048 + kv0 + blk * 8,
                  &Vs[buf][chunk * 8][0]);
    }
  };

  bf16x8 qf0[4], qf1[4];
  {
    const unsigned short* qp0 =
        qkv + rowbase + (size_t)(qw + l31) * C3 + hoff + h * 8;
    const unsigned short* qp1 = qp0 + 32 * C3;
#pragma unroll
    for (int s = 0; s < 4; ++s) {
      qf0[s] = *(const bf16x8*)(qp0 + 16 * s);
      qf1[s] = *(const bf16x8*)(qp1 + 16 * s);
    }
  }

  f32x16 oacc0[2] = {}, oacc1[2] = {};
  float mr0 = -1e30f, mr1 = -1e30f, sum0 = 0.f, sum1 = 0.f;

  stageK(0, 0);
  stageV(0, 0);

  auto do_half = [&](f32x16 (&sacc)[2], int qx, float& mr, float& sm,
                     f32x16 (&oc)[2], int t, int kv0, int cur) {
    if (kv0 + 64 > qx) {
      int q_abs = qx + l31;
#pragma unroll
      for (int kt = 0; kt < 2; ++kt)
#pragma unroll
        for (int r = 0; r < 16; ++r) {
          int kv_abs = kv0 + kt * 32 + (r & 3) + 8 * (r >> 2) + 4 * h;
          if (kv_abs > q_abs) sacc[kt][r] = -1e30f;
        }
    }
    float mx[8];
#pragma unroll
    for (int g = 0; g < 8; ++g)
      mx[g] = fmaxf(fmaxf(sacc[g >> 2][(g & 3) * 4 + 0],
                          sacc[g >> 2][(g & 3) * 4 + 1]),
                    fmaxf(sacc[g >> 2][(g & 3) * 4 + 2],
                          sacc[g >> 2][(g & 3) * 4 + 3]));
    float tm = fmaxf(fmaxf(fmaxf(mx[0], mx[1]), fmaxf(mx[2], mx[3])),
                     fmaxf(fmaxf(mx[4], mx[5]), fmaxf(mx[6], mx[7])));
    tm = fmaxf(tm, __shfl_xor(tm, 32));
    if (t == 0) {
      mr = tm;
    } else if (!__all(tm <= mr + 16.0f)) {
      float mnew = fmaxf(mr, tm);
      float corr = __builtin_amdgcn_exp2f((mr - mnew) * c2);
      sm *= corr;
      if (h == 0) Bc[w][l31] = corr;
      mr = mnew;
      asm volatile("s_waitcnt lgkmcnt(0)" ::: "memory");
#pragma unroll
      for (int r = 0; r < 16; ++r) {
        float cr = Bc[w][(r & 3) + 8 * (r >> 2) + 4 * h];
        oc[0][r] *= cr;
        oc[1][r] *= cr;
      }
    }
    float m2 = mr * c2;
    float s0 = 0.f, s1 = 0.f, s2 = 0.f, s3 = 0.f;
#pragma unroll
    for (int kt = 0; kt < 2; ++kt)
#pragma unroll
      for (int r = 0; r < 16; r += 4) {
        float p0 = __builtin_amdgcn_exp2f(fmaf(sacc[kt][r + 0], c2, -m2));
        float p1 = __builtin_amdgcn_exp2f(fmaf(sacc[kt][r + 1], c2, -m2));
        float p2 = __builtin_amdgcn_exp2f(fmaf(sacc[kt][r + 2], c2, -m2));
        float p3 = __builtin_amdgcn_exp2f(fmaf(sacc[kt][r + 3], c2, -m2));
        sacc[kt][r + 0] = p0; sacc[kt][r + 1] = p1;
        sacc[kt][r + 2] = p2; sacc[kt][r + 3] = p3;
        s0 += p0; s1 += p1; s2 += p2; s3 += p3;
      }
    float sl = (s0 + s1) + (s2 + s3);
    sm += sl + __shfl_xor(sl, 32);
    unsigned pk[16];
#pragma unroll
    for (int kt = 0; kt < 2; ++kt)
#pragma unroll
      for (int r = 0; r < 16; r += 2)
        pk[kt * 8 + (r >> 1)] = cvt_pk_bf16(sacc[kt][r], sacc[kt][r + 1]);
    __builtin_amdgcn_s_setprio(1);
#pragma unroll
    for (int sg = 0; sg < 4; ++sg) {
      const int kt = sg >> 1, s = sg & 1;
      const int base = kt * 8 + 4 * s;
      uint2v r02 = __builtin_amdgcn_permlane32_swap(pk[base], pk[base + 2],
                                                    false, false);
      uint2v r13 = __builtin_amdgcn_permlane32_swap(pk[base + 1], pk[base + 3],
                                                    false, false);
      union { unsigned u[4]; bf16x8 v; } Afr;
      Afr.u[0] = r02.x; Afr.u[1] = r13.x;
      Afr.u[2] = r02.y; Afr.u[3] = r13.y;
#pragma unroll
      for (int dt = 0; dt < 2; ++dt) {
        int d = dt * 32 + l31;
        int blk = (2 * sg + h) ^ (d & 7);
        bf16x8 vf = *(const bf16x8*)&Vs[cur][d][blk * 8];
        oc[dt] = __builtin_amdgcn_mfma_f32_32x32x16_bf16(Afr.v, vf,
                                                         oc[dt], 0, 0, 0);
      }
    }
    __builtin_amdgcn_s_setprio(0);
  };

  int cur = 0;
  const int ntiles = 4 * qt + 4;
  for (int t = 0; t < ntiles; ++t) {
    const int kv0 = t * 64;
    __builtin_amdgcn_s_barrier();
    if (t + 1 < ntiles) {
      stageK(kv0 + 64, cur ^ 1);
      stageV(kv0 + 64, cur ^ 1);
      asm volatile("s_waitcnt vmcnt(4)" ::: "memory");
    } else {
      asm volatile("s_waitcnt vmcnt(0)" ::: "memory");
    }
    __builtin_amdgcn_s_barrier();
    __builtin_amdgcn_sched_barrier(0);

    if (kv0 <= qw) {
      f32x16 sacc0[2] = {}, sacc1[2] = {};
      __builtin_amdgcn_s_setprio(1);
#pragma unroll
      for (int s = 0; s < 4; ++s) {
#pragma unroll
        for (int kt = 0; kt < 2; ++kt) {
          int row = kt * 32 + l31;
          int blk = (2 * s + h) ^ (row & 7);
          bf16x8 kf = *(const bf16x8*)&Ks[cur][row][blk * 8];
          sacc0[kt] = __builtin_amdgcn_mfma_f32_32x32x16_bf16(kf, qf0[s],
                                                              sacc0[kt], 0, 0, 0);
          sacc1[kt] = __builtin_amdgcn_mfma_f32_32x32x16_bf16(kf, qf1[s],
                                                              sacc1[kt], 0, 0, 0);
        }
      }
      __builtin_amdgcn_s_setprio(0);
      do_half(sacc0, qw, mr0, sum0, oacc0, t, kv0, cur);
      do_half(sacc1, qw + 32, mr1, sum1, oacc1, t, kv0, cur);
    }
    cur ^= 1;
  }

#pragma unroll
  for (int X = 0; X < 2; ++X) {
    float sm = X ? sum1 : sum0;
    if (h == 0) Bc[w][l31] = 1.0f / sm;
    asm volatile("s_waitcnt lgkmcnt(0)" ::: "memory");
#pragma unroll
    for (int r = 0; r < 16; ++r) {
      int ql = (r & 3) + 8 * (r >> 2) + 4 * h;
      float inv = Bc[w][ql];
      int q_abs = qw + 32 * X + ql;
#pragma unroll
      for (int dt = 0; dt < 2; ++dt) {
        float v = (X ? oacc1 : oacc0)[dt][r] * inv;
        out[(size_t)(b * T + q_abs) * 1024 + hoff + dt * 32 + l31] =
            f2b_rne(v);
      }
    }
    __builtin_amdgcn_s_barrier();  // Bc reuse between halves
  }
}

// ---------------------------------------------------------------------------
extern "C" void kernel_launch(void* const* d_in, const int* in_sizes, int n_in,
                              void* d_out, int out_size, void* d_ws,
                              size_t ws_size, hipStream_t stream) {
  const float* x = (const float*)d_in[0];      // [4,2048,1024]
  const float* w_qkv = (const float*)d_in[1];  // [3072,1024]
  const float* w_out = (const float*)d_in[2];  // [1024,1024]
  float* out = (float*)d_out;                  // [4,2048,1024] fp32

  const int M = 8192, C = 1024, C3 = 3072;

  unsigned short* xb = (unsigned short*)d_ws;      // M*C  (reused as attno)
  unsigned short* wqkvb = xb + (size_t)M * C;      // C3*C
  unsigned short* woutb = wqkvb + (size_t)C3 * C;  // C*C
  unsigned short* qkv = woutb + (size_t)C * C;     // M*C3
  unsigned short* vtb = qkv + (size_t)M * C3;      // B*H*64*T = M*C
  unsigned short* attno = xb;                      // alias: xb dead post-GEMM1

  f32_to_bf16_vec<<<1024, 256, 0, stream>>>(x, xb, M * C / 4);
  f32_to_bf16_vec<<<512, 256, 0, stream>>>(w_qkv, wqkvb, C3 * C / 4);
  f32_to_bf16_vec<<<256, 256, 0, stream>>>(w_out, woutb, C * C / 4);

  gemm_big<3072, 1><<<768, 512, 0, stream>>>(xb, wqkvb, qkv);

  v_transpose<<<dim3(32, 64), 256, 0, stream>>>(qkv, vtb);

  attn_fwd<<<512, 256, 0, stream>>>(qkv, vtb, attno);

  gemm_big<1024, 0><<<256, 512, 0, stream>>>(attno, woutb, out);
}